// Round 12
// baseline (634.564 us; speedup 1.0000x reference)
//
#include <hip/hip_runtime.h>
#include <hip/hip_bf16.h>

#define NNODE 50000
#define NEDGE 800000
#define NGRAPH 128
#define DIN 200
#define DH 128
#define OUTW (DIN + 4*DH)   // 712
#define NB 196              // node buckets of 256 rows
#define NSLOT 32            // stat partial slots

typedef short bf16x8 __attribute__((ext_vector_type(8)));
typedef float f32x4  __attribute__((ext_vector_type(4)));

__device__ __forceinline__ short f2bf(float f) {
    union { float f; unsigned u; } x; x.f = f;
    unsigned u = x.u;
    u += 0x7fffu + ((u >> 16) & 1u);   // RNE
    return (short)(u >> 16);
}
__device__ __forceinline__ float bflo(unsigned v) {
    union { unsigned u; float f; } x; x.u = v << 16; return x.f;
}
__device__ __forceinline__ float bfhi(unsigned v) {
    union { unsigned u; float f; } x; x.u = v & 0xffff0000u; return x.f;
}
__device__ __forceinline__ float bfs(unsigned short v) {
    union { unsigned u; float f; } x; x.u = ((unsigned)v) << 16; return x.f;
}
__device__ __forceinline__ unsigned pkbf(float lo, float hi) {
    __hip_bfloat162 p = __float22bfloat162_rn(float2{lo, hi});
    unsigned u; __builtin_memcpy(&u, &p, 4); return u;
}

// ---------------- pre-zero: bcnt must be zero BEFORE the setup dispatch that histograms into it
__global__ __launch_bounds__(256) void prezero_kernel(int* __restrict__ bcnt) {
    bcnt[threadIdx.x] = 0;
}

// ---------------- mega-setup: zero out/stats, gs bounds, wconv, histB ----------------
__global__ __launch_bounds__(256) void setup_kernel(
    float* __restrict__ out, float* __restrict__ statz, int* __restrict__ bcnt,
    const int* __restrict__ gid, int* __restrict__ gs,
    const float* __restrict__ w1_0, const float* __restrict__ w2_0,
    const float* __restrict__ w1_r, const float* __restrict__ w2_r, short* __restrict__ Wt,
    const int* __restrict__ erow)
{
    __shared__ int lh[224];
    int b = blockIdx.x, t = threadIdx.x;
    if (b < 356) {                       // zero ALL of out: 712*128 = 91136 = 356*256
        out[b * 256 + t] = 0.f;
    } else if (b < 612) {                // stats: 4 layers * 4 arrays * 32*128 = 65536 floats
        statz[(b - 356) * 256 + t] = 0.f;
    } else if (b == 612) {
        // (bcnt zeroing in prezero_kernel -- intra-dispatch race fix)
    } else if (b == 613) {
        if (t <= NGRAPH) {
            int lo = 0, hi = NNODE;
            while (lo < hi) { int m = (lo + hi) >> 1; if (gid[m] < t) lo = m + 1; else hi = m; }
            gs[t] = lo;
        }
    } else if (b < 614 + 896) {          // wconv: 8 matrices
        int wb = b - 614;
        int m = wb / 112, sub = wb % 112;
        int idx = sub * 256 + t;
        int KP = (m == 0) ? 224 : 128;
        if (idx < KP * DH) {
            int k = idx >> 7, c = idx & 127;
            const float* src = (m == 0) ? w1_0 : (m == 1) ? w2_0
                             : ((m & 1) == 0 ? w1_r + (size_t)((m - 2) >> 1) * DH * DH
                                             : w2_r + (size_t)((m - 3) >> 1) * DH * DH);
            int KREAL = (m == 0) ? 200 : 128;
            float v = (k < KREAL) ? src[k * DH + c] : 0.f;
            short* dst = Wt + ((m == 0) ? 0 : 28672 + (m - 1) * 16384);
            dst[c * KP + k] = f2bf(v);
        }
    } else {                             // histB: 782 blocks
        int hb = b - 1510;
        if (t < 224) lh[t] = 0;
        __syncthreads();
        int base = hb * 1024;
        #pragma unroll
        for (int i = 0; i < 4; ++i) {
            int e = base + i * 256 + t;
            if (e < NEDGE) atomicAdd(&lh[erow[e] >> 8], 1);
        }
        __syncthreads();
        if (t < NB && lh[t]) atomicAdd(&bcnt[t], lh[t]);
    }
}

// ---------------- CSR build ----------------
__global__ __launch_bounds__(256) void scanB_kernel(const int* __restrict__ bcnt, int* __restrict__ boff,
                                                    int* __restrict__ bcur, int* __restrict__ off) {
    __shared__ int sd[256];
    int t = threadIdx.x;
    int v = (t < NB) ? bcnt[t] : 0;
    sd[t] = v; __syncthreads();
    for (int s = 1; s < 256; s <<= 1) {
        int x = (t >= s) ? sd[t - s] : 0;
        __syncthreads(); sd[t] += x; __syncthreads();
    }
    if (t < NB) { boff[t] = sd[t] - v; bcur[t] = 0; }
    if (t == 0) { boff[NB] = NEDGE; off[NNODE] = NEDGE; }
}

__global__ __launch_bounds__(256) void scatterA_kernel(const int* __restrict__ erow, const int* __restrict__ ecol,
                                                       const int* __restrict__ boff, int* __restrict__ bcur,
                                                       unsigned* __restrict__ bdata) {
    __shared__ int lh[224], gb[224];
    int t = threadIdx.x;
    if (t < 224) lh[t] = 0;
    __syncthreads();
    int base = blockIdx.x * 1024;
    int bb[4], rk[4]; unsigned pk[4];
    #pragma unroll
    for (int i = 0; i < 4; ++i) {
        int e = base + i * 256 + t;
        if (e < NEDGE) {
            int r = erow[e];
            bb[i] = r >> 8;
            pk[i] = ((unsigned)(r & 255) << 16) | (unsigned)ecol[e];
            rk[i] = atomicAdd(&lh[bb[i]], 1);
        } else bb[i] = -1;
    }
    __syncthreads();
    if (t < NB && lh[t] > 0) gb[t] = atomicAdd(&bcur[t], lh[t]);
    __syncthreads();
    #pragma unroll
    for (int i = 0; i < 4; ++i) {
        if (bb[i] >= 0) bdata[boff[bb[i]] + gb[bb[i]] + rk[i]] = pk[i];
    }
}

__global__ __launch_bounds__(256) void bucketB_kernel(const unsigned* __restrict__ bdata, const int* __restrict__ boff,
                                                      int* __restrict__ off, unsigned short* __restrict__ ccol) {
    __shared__ int lh[256], loff[256], lcur[256];
    int b = blockIdx.x, t = threadIdx.x;
    lh[t] = 0; lcur[t] = 0;
    __syncthreads();
    int lo = boff[b], hi = boff[b + 1];
    for (int e = lo + t; e < hi; e += 256) atomicAdd(&lh[bdata[e] >> 16], 1);
    __syncthreads();
    loff[t] = lh[t]; __syncthreads();
    for (int s = 1; s < 256; s <<= 1) {
        int x = (t >= s) ? loff[t - s] : 0;
        __syncthreads(); loff[t] += x; __syncthreads();
    }
    int row = b * 256 + t;
    if (row < NNODE) off[row] = lo + loff[t] - lh[t];
    __syncthreads();
    for (int e = lo + t; e < hi; e += 256) {
        unsigned v = bdata[e];
        int rlo = v >> 16;
        int p = atomicAdd(&lcur[rlo], 1);
        ccol[lo + loff[rlo] - lh[rlo] + p] = (unsigned short)(v & 0xffffu);
    }
}

// ---------------- BN params: tiny 1-block reduction (removes per-block prologues) ----------------
__global__ __launch_bounds__(128) void colparams_kernel(
    const float* __restrict__ ps, const float* __restrict__ pq,
    const float* __restrict__ gamma, const float* __restrict__ bbeta,
    float* __restrict__ al, float* __restrict__ be)
{
    int c = threadIdx.x;
    float s = 0.f, q = 0.f;
    #pragma unroll 8
    for (int i = 0; i < NSLOT; ++i) { s += ps[i * DH + c]; q += pq[i * DH + c]; }
    float mean = s * (1.f / NNODE);
    float var  = fmaxf(q * (1.f / NNODE) - mean * mean, 0.f);
    float a    = gamma[c] * rsqrtf(var + 1e-5f);
    al[c] = a; be[c] = bbeta[c] - a * mean;
}

// ---------------- GEMM: C[NNODE][128] = act(A) @ W, full A-prefetch for MLP ----------------
template<int KSTEPS, int KREAL, bool ABF16, bool FUSE, bool STATS>
__global__ __launch_bounds__(256, 4) void gemm_kernel(
    const void* __restrict__ Ap, const short* __restrict__ Wt,
    const float* __restrict__ al, const float* __restrict__ be,
    short* __restrict__ C, float* __restrict__ psOut, float* __restrict__ pqOut)
{
    constexpr int KP = KSTEPS * 32;
    __shared__ float sS[DH], sQ[DH];
    int tid = threadIdx.x;
    if constexpr (STATS) {
        if (tid < DH) { sS[tid] = 0.f; sQ[tid] = 0.f; }
        __syncthreads();
    }

    int wave = tid >> 6, lane = tid & 63;
    int lr = lane & 15, lk = lane >> 4;
    int row  = blockIdx.x * 64 + wave * 16 + lr;
    int ksub = lk * 8;
    bool rok = row < NNODE;
    const short* wbase = Wt + (size_t)lr * KP + ksub;

    f32x4 acc[8];
    #pragma unroll
    for (int n = 0; n < 8; ++n) acc[n] = (f32x4){0.f, 0.f, 0.f, 0.f};

    if constexpr (ABF16) {
        // prefetch ALL A fragments up front -> KSTEPS loads in flight
        bf16x8 araw[KSTEPS];
        #pragma unroll
        for (int kk = 0; kk < KSTEPS; ++kk) {
            if (rok) araw[kk] = *(const bf16x8*)((const short*)Ap + (size_t)row * KREAL + kk * 32 + ksub);
            else     araw[kk] = (bf16x8){0,0,0,0,0,0,0,0};
        }
        #pragma unroll
        for (int kk = 0; kk < KSTEPS; ++kk) {
            int k0 = kk * 32 + ksub;
            union { bf16x8 v; unsigned u[4]; } raw; raw.v = araw[kk];
            float va[8];
            #pragma unroll
            for (int e = 0; e < 4; ++e) { va[2*e] = bflo(raw.u[e]); va[2*e+1] = bfhi(raw.u[e]); }
            if constexpr (FUSE) {
                const float4* ap = (const float4*)(al + k0);
                const float4* bp = (const float4*)(be + k0);
                float4 A0 = ap[0], A1 = ap[1], B0 = bp[0], B1 = bp[1];
                va[0]=fmaxf(A0.x*va[0]+B0.x,0.f); va[1]=fmaxf(A0.y*va[1]+B0.y,0.f);
                va[2]=fmaxf(A0.z*va[2]+B0.z,0.f); va[3]=fmaxf(A0.w*va[3]+B0.w,0.f);
                va[4]=fmaxf(A1.x*va[4]+B1.x,0.f); va[5]=fmaxf(A1.y*va[5]+B1.y,0.f);
                va[6]=fmaxf(A1.z*va[6]+B1.z,0.f); va[7]=fmaxf(A1.w*va[7]+B1.w,0.f);
            }
            union { bf16x8 v; unsigned u[4]; } a;
            #pragma unroll
            for (int e = 0; e < 4; ++e) a.u[e] = pkbf(va[2*e], va[2*e+1]);
            #pragma unroll
            for (int n = 0; n < 8; ++n) {
                bf16x8 bfrag = *(const bf16x8*)(wbase + (size_t)n * 16 * KP + kk * 32);
                acc[n] = __builtin_amdgcn_mfma_f32_16x16x32_bf16(a.v, bfrag, acc[n], 0, 0, 0);
            }
        }
    } else {
        // f32 A, 2-deep prefetch pipeline
        const float* arow = (const float*)Ap + (size_t)row * KREAL;
        float4 c0, c1, n0, n1;
        bool v0 = rok && (ksub + 8 <= KREAL);
        if (v0) { const float4* p = (const float4*)(arow + ksub); c0 = p[0]; c1 = p[1]; }
        else    { c0 = float4{0,0,0,0}; c1 = float4{0,0,0,0}; }
        #pragma unroll
        for (int kk = 0; kk < KSTEPS; ++kk) {
            if (kk + 1 < KSTEPS) {
                int k1 = (kk + 1) * 32 + ksub;
                bool vn = rok && (k1 + 8 <= KREAL);
                if (vn) { const float4* p = (const float4*)(arow + k1); n0 = p[0]; n1 = p[1]; }
                else    { n0 = float4{0,0,0,0}; n1 = float4{0,0,0,0}; }
            }
            float va[8];
            va[0]=c0.x; va[1]=c0.y; va[2]=c0.z; va[3]=c0.w;
            va[4]=c1.x; va[5]=c1.y; va[6]=c1.z; va[7]=c1.w;
            union { bf16x8 v; unsigned u[4]; } a;
            #pragma unroll
            for (int e = 0; e < 4; ++e) a.u[e] = pkbf(va[2*e], va[2*e+1]);
            #pragma unroll
            for (int n = 0; n < 8; ++n) {
                bf16x8 bfrag = *(const bf16x8*)(wbase + (size_t)n * 16 * KP + kk * 32);
                acc[n] = __builtin_amdgcn_mfma_f32_16x16x32_bf16(a.v, bfrag, acc[n], 0, 0, 0);
            }
            c0 = n0; c1 = n1;
        }
    }

    int orow = blockIdx.x * 64 + wave * 16 + lk * 4;
    #pragma unroll
    for (int n = 0; n < 8; ++n) {
        #pragma unroll
        for (int j = 0; j < 4; ++j) {
            int rr = orow + j;
            if (rr < NNODE) C[(size_t)rr * DH + n * 16 + lr] = f2bf(acc[n][j]);
        }
    }

    if constexpr (STATS) {
        #pragma unroll
        for (int n = 0; n < 8; ++n) {
            float sv = 0.f, qv = 0.f;
            #pragma unroll
            for (int j = 0; j < 4; ++j) {
                if (orow + j < NNODE) { float v = acc[n][j]; sv += v; qv += v * v; }
            }
            atomicAdd(&sS[n * 16 + lr], sv);
            atomicAdd(&sQ[n * 16 + lr], qv);
        }
        __syncthreads();
        if (tid < DH) {
            int slot = (blockIdx.x & (NSLOT - 1)) * DH + tid;
            atomicAdd(&psOut[slot], sS[tid]); atomicAdd(&pqOut[slot], sQ[tid]);
        }
    }
}

// ---------------- aggregation: z = Adj@y + (1+eps)*y, bf16 in/out, NO stats, NT z-store ----------------
__global__ __launch_bounds__(256) void agg_kernel(
    const short* __restrict__ yb, short* __restrict__ zb,
    const int* __restrict__ off, const unsigned short* __restrict__ ccol,
    const float* __restrict__ epsv, int layer)
{
    int tid = threadIdx.x;
    int wave = tid >> 6, t = tid & 63;
    int node = blockIdx.x * 4 + wave;
    if (node >= NNODE) return;
    const unsigned* y2 = (const unsigned*)yb;
    int k = off[node], k1 = off[node + 1];
    float s0=0,s1=0,t0=0,t1=0,u0=0,u1=0,v0=0,v1=0;
    for (; k + 7 < k1; k += 8) {
        int c0 = ccol[k],   c1 = ccol[k+1], c2 = ccol[k+2], c3 = ccol[k+3];
        int c4 = ccol[k+4], c5 = ccol[k+5], c6 = ccol[k+6], c7 = ccol[k+7];
        unsigned a = y2[(size_t)c0 * 64 + t];
        unsigned b = y2[(size_t)c1 * 64 + t];
        unsigned c = y2[(size_t)c2 * 64 + t];
        unsigned d = y2[(size_t)c3 * 64 + t];
        unsigned e = y2[(size_t)c4 * 64 + t];
        unsigned f = y2[(size_t)c5 * 64 + t];
        unsigned g = y2[(size_t)c6 * 64 + t];
        unsigned h = y2[(size_t)c7 * 64 + t];
        s0 += bflo(a) + bflo(e); s1 += bfhi(a) + bfhi(e);
        t0 += bflo(b) + bflo(f); t1 += bfhi(b) + bfhi(f);
        u0 += bflo(c) + bflo(g); u1 += bfhi(c) + bfhi(g);
        v0 += bflo(d) + bflo(h); v1 += bfhi(d) + bfhi(h);
    }
    for (; k + 3 < k1; k += 4) {
        int c0 = ccol[k], c1 = ccol[k+1], c2 = ccol[k+2], c3 = ccol[k+3];
        unsigned a = y2[(size_t)c0 * 64 + t];
        unsigned b = y2[(size_t)c1 * 64 + t];
        unsigned c = y2[(size_t)c2 * 64 + t];
        unsigned d = y2[(size_t)c3 * 64 + t];
        s0 += bflo(a); s1 += bfhi(a); t0 += bflo(b); t1 += bfhi(b);
        u0 += bflo(c); u1 += bfhi(c); v0 += bflo(d); v1 += bfhi(d);
    }
    for (; k < k1; ++k) {
        unsigned a = y2[(size_t)ccol[k] * 64 + t];
        s0 += bflo(a); s1 += bfhi(a);
    }
    unsigned sv = y2[(size_t)node * 64 + t];
    float e = 1.f + epsv[layer];
    float rx = (s0 + t0) + (u0 + v0) + e * bflo(sv);
    float ry = (s1 + t1) + (u1 + v1) + e * bfhi(sv);
    __builtin_nontemporal_store(pkbf(rx, ry), (unsigned*)zb + (size_t)node * 64 + t);
}

// ---------------- Z BN stats (separate pass, vectorized) ----------------
__global__ __launch_bounds__(256) void statsZ_kernel(const short* __restrict__ zb,
                                                     float* __restrict__ ps, float* __restrict__ pq) {
    __shared__ float red[4][DH];
    int t = threadIdx.x;
    int cg = t & 63, rg = t >> 6;
    const unsigned* z2 = (const unsigned*)zb;
    int r0 = blockIdx.x * 196, r1 = min(r0 + 196, NNODE);
    float s0 = 0.f, s1 = 0.f, q0 = 0.f, q1 = 0.f;
    for (int r = r0 + rg; r < r1; r += 4) {
        unsigned v = z2[(size_t)r * 64 + cg];
        float a = bflo(v), b = bfhi(v);
        s0 += a; q0 += a * a; s1 += b; q1 += b * b;
    }
    red[rg][2 * cg] = s0; red[rg][2 * cg + 1] = s1;
    __syncthreads();
    if (t < DH) {
        float s = red[0][t] + red[1][t] + red[2][t] + red[3][t];
        atomicAdd(&ps[(blockIdx.x & (NSLOT - 1)) * DH + t], s);
    }
    __syncthreads();
    red[rg][2 * cg] = q0; red[rg][2 * cg + 1] = q1;
    __syncthreads();
    if (t < DH) {
        float q = red[0][t] + red[1][t] + red[2][t] + red[3][t];
        atomicAdd(&pq[(blockIdx.x & (NSLOT - 1)) * DH + t], q);
    }
}

// ---------------- pooling ----------------
__global__ __launch_bounds__(256) void poolx_kernel(const float* __restrict__ x,
                                                    const int* __restrict__ gs, float* __restrict__ out) {
    int g = blockIdx.x >> 4, sp = blockIdx.x & 15, t = threadIdx.x;
    if (t >= DIN) return;
    int lo = gs[g], hi = gs[g + 1], len = hi - lo;
    int r0 = lo + (len * sp >> 4), r1 = lo + (len * (sp + 1) >> 4);
    float a0 = 0.f, a1 = 0.f;
    int r = r0;
    for (; r + 1 < r1; r += 2) {
        a0 += x[(size_t)r * DIN + t];
        a1 += x[(size_t)(r + 1) * DIN + t];
    }
    if (r < r1) a0 += x[(size_t)r * DIN + t];
    atomicAdd(&out[g * OUTW + t], a0 + a1);
}

__global__ __launch_bounds__(128) void pool_kernel(const short* __restrict__ rep,
                                                   const float* __restrict__ al, const float* __restrict__ be,
                                                   const int* __restrict__ gs, float* __restrict__ out, int ooff) {
    int c = threadIdx.x;
    float a = al[c], b = be[c];
    int g = blockIdx.x >> 3, sp = blockIdx.x & 7;
    int lo = gs[g], hi = gs[g + 1], len = hi - lo;
    int r0 = lo + (len * sp >> 3), r1 = lo + (len * (sp + 1) >> 3);
    float acc = 0.f;
    const unsigned short* rp = (const unsigned short*)rep;
    for (int r = r0; r < r1; ++r) acc += fmaxf(a * bfs(rp[(size_t)r * DH + c]) + b, 0.f);
    atomicAdd(&out[g * OUTW + ooff + c], acc);
}

// ---------------- launch ----------------
extern "C" void kernel_launch(void* const* d_in, const int* in_sizes, int n_in,
                              void* d_out, int out_size, void* d_ws, size_t ws_size,
                              hipStream_t stream)
{
    const float* x    = (const float*)d_in[0];
    const int*   erow = (const int*)d_in[1];
    const int*   ecol = (const int*)d_in[2];
    const int*   gid  = (const int*)d_in[3];
    const float* eps  = (const float*)d_in[4];
    const float* w1_0 = (const float*)d_in[5];
    const float* g1_0 = (const float*)d_in[7];
    const float* be10 = (const float*)d_in[8];
    const float* w2_0 = (const float*)d_in[9];
    const float* gbn0 = (const float*)d_in[11];
    const float* bbn0 = (const float*)d_in[12];
    const float* w1_r = (const float*)d_in[13];
    const float* g1_r = (const float*)d_in[15];
    const float* be1r = (const float*)d_in[16];
    const float* w2_r = (const float*)d_in[17];
    const float* gbnr = (const float*)d_in[19];
    const float* bbnr = (const float*)d_in[20];
    float* out = (float*)d_out;

    // workspace layout
    short* Zb = (short*)d_ws;                       // NNODE*DH bf16
    short* Y  = Zb + (size_t)NNODE * DH;
    short* RA = Y  + (size_t)NNODE * DH;
    short* RB = RA + (size_t)NNODE * DH;
    short* Wt = RB + (size_t)NNODE * DH;            // 143360 shorts
    float* stats = (float*)(Wt + 143360);           // 4 layers * 4 * NSLOT*DH = 65536 floats
    float* a1v = stats + 65536;                     // 4 x 128 BN param buffers
    float* b1v = a1v + DH;
    float* a2v = b1v + DH;
    float* b2v = a2v + DH;
    int* bcnt = (int*)(b2v + DH);                   // 256
    int* boff = bcnt + 256;
    int* bcur = boff + 256;
    int* off  = bcur + 256;                         // 50016
    unsigned* bdata = (unsigned*)(off + 50016);     // NEDGE
    unsigned short* ccol = (unsigned short*)(bdata + NEDGE);  // NEDGE u16
    int* gs = (int*)(ccol + NEDGE);                 // 129

    prezero_kernel<<<1, 256, 0, stream>>>(bcnt);
    setup_kernel<<<2292, 256, 0, stream>>>(out, stats, bcnt, gid, gs,
                                           w1_0, w2_0, w1_r, w2_r, Wt, erow);
    scanB_kernel<<<1, 256, 0, stream>>>(bcnt, boff, bcur, off);
    scatterA_kernel<<<782, 256, 0, stream>>>(erow, ecol, boff, bcur, bdata);
    bucketB_kernel<<<NB, 256, 0, stream>>>(bdata, boff, off, ccol);
    poolx_kernel<<<NGRAPH * 16, 256, 0, stream>>>(x, gs, out);

    const int GB = (NNODE + 63) / 64;   // 782
    const int LS = NSLOT * DH;
    for (int l = 0; l < 4; ++l) {
        const short* Wt1 = (l == 0) ? Wt : Wt + 28672 + (size_t)(2 * l - 1) * 16384;
        const short* Wt2 = (l == 0) ? Wt + 28672 : Wt + 28672 + (size_t)(2 * l) * 16384;
        const float* G1 = (l == 0) ? g1_0 : (g1_r + (l - 1) * DH);
        const float* B1 = (l == 0) ? be10 : (be1r + (l - 1) * DH);
        const float* G2 = (l == 0) ? gbn0 : (gbnr + (l - 1) * DH);
        const float* B2 = (l == 0) ? bbn0 : (bbnr + (l - 1) * DH);
        short* rep = (l & 1) ? RB : RA;
        float* psZ = stats + l * 4 * LS;
        float* pqZ = psZ + LS;
        float* psA = pqZ + LS;
        float* pqA = psA + LS;

        if (l == 0)
            gemm_kernel<7, 200, false, false, false><<<GB, 256, 0, stream>>>(
                x, Wt1, nullptr, nullptr, Y, nullptr, nullptr);
        else {
            const short* prev = ((l - 1) & 1) ? RB : RA;
            gemm_kernel<4, 128, true, true, false><<<GB, 256, 0, stream>>>(
                prev, Wt1, a2v, b2v, Y, nullptr, nullptr);
        }
        agg_kernel<<<(NNODE + 3) / 4, 256, 0, stream>>>(Y, Zb, off, ccol, eps, l);
        statsZ_kernel<<<256, 256, 0, stream>>>(Zb, psZ, pqZ);
        colparams_kernel<<<1, 128, 0, stream>>>(psZ, pqZ, G1, B1, a1v, b1v);
        gemm_kernel<4, 128, true, true, true><<<GB, 256, 0, stream>>>(
            Zb, Wt2, a1v, b1v, rep, psA, pqA);
        colparams_kernel<<<1, 128, 0, stream>>>(psA, pqA, G2, B2, a2v, b2v);
        pool_kernel<<<NGRAPH * 8, 128, 0, stream>>>(rep, a2v, b2v, gs, out, DIN + l * DH);
    }
}

// Round 13
// 545.198 us; speedup vs baseline: 1.1639x; 1.1639x over previous
//
#include <hip/hip_runtime.h>
#include <hip/hip_bf16.h>

#define NNODE 50000
#define NEDGE 800000
#define NGRAPH 128
#define DIN 200
#define DH 128
#define OUTW (DIN + 4*DH)   // 712
#define NB 196              // node buckets of 256 rows
#define NSLOT 32            // stat partial slots

typedef short bf16x8 __attribute__((ext_vector_type(8)));
typedef float f32x4  __attribute__((ext_vector_type(4)));

__device__ __forceinline__ short f2bf(float f) {
    union { float f; unsigned u; } x; x.f = f;
    unsigned u = x.u;
    u += 0x7fffu + ((u >> 16) & 1u);   // RNE
    return (short)(u >> 16);
}
__device__ __forceinline__ float bflo(unsigned v) {
    union { unsigned u; float f; } x; x.u = v << 16; return x.f;
}
__device__ __forceinline__ float bfhi(unsigned v) {
    union { unsigned u; float f; } x; x.u = v & 0xffff0000u; return x.f;
}
__device__ __forceinline__ float bfs(unsigned short v) {
    union { unsigned u; float f; } x; x.u = ((unsigned)v) << 16; return x.f;
}
__device__ __forceinline__ unsigned pkbf(float lo, float hi) {
    __hip_bfloat162 p = __float22bfloat162_rn(float2{lo, hi});
    unsigned u; __builtin_memcpy(&u, &p, 4); return u;
}

// ---------------- pre-zero: bcnt must be zero BEFORE the setup dispatch that histograms into it
__global__ __launch_bounds__(256) void prezero_kernel(int* __restrict__ bcnt) {
    bcnt[threadIdx.x] = 0;
}

// ---------------- mega-setup: zero out/stats, gs bounds, wconv, histB ----------------
__global__ __launch_bounds__(256) void setup_kernel(
    float* __restrict__ out, float* __restrict__ statz, int* __restrict__ bcnt,
    const int* __restrict__ gid, int* __restrict__ gs,
    const float* __restrict__ w1_0, const float* __restrict__ w2_0,
    const float* __restrict__ w1_r, const float* __restrict__ w2_r, short* __restrict__ Wt,
    const int* __restrict__ erow)
{
    __shared__ int lh[224];
    int b = blockIdx.x, t = threadIdx.x;
    if (b < 356) {                       // zero ALL of out: 712*128 = 91136 = 356*256
        out[b * 256 + t] = 0.f;
    } else if (b < 612) {                // stats: 4 layers * 4 arrays * 32*128 = 65536 floats
        statz[(b - 356) * 256 + t] = 0.f;
    } else if (b == 612) {
        // (bcnt zeroing in prezero_kernel -- intra-dispatch race fix)
    } else if (b == 613) {
        if (t <= NGRAPH) {
            int lo = 0, hi = NNODE;
            while (lo < hi) { int m = (lo + hi) >> 1; if (gid[m] < t) lo = m + 1; else hi = m; }
            gs[t] = lo;
        }
    } else if (b < 614 + 896) {          // wconv: 8 matrices
        int wb = b - 614;
        int m = wb / 112, sub = wb % 112;
        int idx = sub * 256 + t;
        int KP = (m == 0) ? 224 : 128;
        if (idx < KP * DH) {
            int k = idx >> 7, c = idx & 127;
            const float* src = (m == 0) ? w1_0 : (m == 1) ? w2_0
                             : ((m & 1) == 0 ? w1_r + (size_t)((m - 2) >> 1) * DH * DH
                                             : w2_r + (size_t)((m - 3) >> 1) * DH * DH);
            int KREAL = (m == 0) ? 200 : 128;
            float v = (k < KREAL) ? src[k * DH + c] : 0.f;
            short* dst = Wt + ((m == 0) ? 0 : 28672 + (m - 1) * 16384);
            dst[c * KP + k] = f2bf(v);
        }
    } else {                             // histB: 782 blocks
        int hb = b - 1510;
        if (t < 224) lh[t] = 0;
        __syncthreads();
        int base = hb * 1024;
        #pragma unroll
        for (int i = 0; i < 4; ++i) {
            int e = base + i * 256 + t;
            if (e < NEDGE) atomicAdd(&lh[erow[e] >> 8], 1);
        }
        __syncthreads();
        if (t < NB && lh[t]) atomicAdd(&bcnt[t], lh[t]);
    }
}

// ---------------- CSR build ----------------
__global__ __launch_bounds__(256) void scanB_kernel(const int* __restrict__ bcnt, int* __restrict__ boff,
                                                    int* __restrict__ bcur, int* __restrict__ off) {
    __shared__ int sd[256];
    int t = threadIdx.x;
    int v = (t < NB) ? bcnt[t] : 0;
    sd[t] = v; __syncthreads();
    for (int s = 1; s < 256; s <<= 1) {
        int x = (t >= s) ? sd[t - s] : 0;
        __syncthreads(); sd[t] += x; __syncthreads();
    }
    if (t < NB) { boff[t] = sd[t] - v; bcur[t] = 0; }
    if (t == 0) { boff[NB] = NEDGE; off[NNODE] = NEDGE; }
}

__global__ __launch_bounds__(256) void scatterA_kernel(const int* __restrict__ erow, const int* __restrict__ ecol,
                                                       const int* __restrict__ boff, int* __restrict__ bcur,
                                                       unsigned* __restrict__ bdata) {
    __shared__ int lh[224], gb[224];
    int t = threadIdx.x;
    if (t < 224) lh[t] = 0;
    __syncthreads();
    int base = blockIdx.x * 1024;
    int bb[4], rk[4]; unsigned pk[4];
    #pragma unroll
    for (int i = 0; i < 4; ++i) {
        int e = base + i * 256 + t;
        if (e < NEDGE) {
            int r = erow[e];
            bb[i] = r >> 8;
            pk[i] = ((unsigned)(r & 255) << 16) | (unsigned)ecol[e];
            rk[i] = atomicAdd(&lh[bb[i]], 1);
        } else bb[i] = -1;
    }
    __syncthreads();
    if (t < NB && lh[t] > 0) gb[t] = atomicAdd(&bcur[t], lh[t]);
    __syncthreads();
    #pragma unroll
    for (int i = 0; i < 4; ++i) {
        if (bb[i] >= 0) bdata[boff[bb[i]] + gb[bb[i]] + rk[i]] = pk[i];
    }
}

__global__ __launch_bounds__(256) void bucketB_kernel(const unsigned* __restrict__ bdata, const int* __restrict__ boff,
                                                      int* __restrict__ off, unsigned short* __restrict__ ccol) {
    __shared__ int lh[256], loff[256], lcur[256];
    int b = blockIdx.x, t = threadIdx.x;
    lh[t] = 0; lcur[t] = 0;
    __syncthreads();
    int lo = boff[b], hi = boff[b + 1];
    for (int e = lo + t; e < hi; e += 256) atomicAdd(&lh[bdata[e] >> 16], 1);
    __syncthreads();
    loff[t] = lh[t]; __syncthreads();
    for (int s = 1; s < 256; s <<= 1) {
        int x = (t >= s) ? loff[t - s] : 0;
        __syncthreads(); loff[t] += x; __syncthreads();
    }
    int row = b * 256 + t;
    if (row < NNODE) off[row] = lo + loff[t] - lh[t];
    __syncthreads();
    for (int e = lo + t; e < hi; e += 256) {
        unsigned v = bdata[e];
        int rlo = v >> 16;
        int p = atomicAdd(&lcur[rlo], 1);
        ccol[lo + loff[rlo] - lh[rlo] + p] = (unsigned short)(v & 0xffffu);
    }
}

// ---------------- BN params: tiny 1-block reduction ----------------
__global__ __launch_bounds__(128) void colparams_kernel(
    const float* __restrict__ ps, const float* __restrict__ pq,
    const float* __restrict__ gamma, const float* __restrict__ bbeta,
    float* __restrict__ al, float* __restrict__ be)
{
    int c = threadIdx.x;
    float s = 0.f, q = 0.f;
    #pragma unroll 8
    for (int i = 0; i < NSLOT; ++i) { s += ps[i * DH + c]; q += pq[i * DH + c]; }
    float mean = s * (1.f / NNODE);
    float var  = fmaxf(q * (1.f / NNODE) - mean * mean, 0.f);
    float a    = gamma[c] * rsqrtf(var + 1e-5f);
    al[c] = a; be[c] = bbeta[c] - a * mean;
}

// ---------------- GEMM: C[NNODE][128] = act(A) @ W; B staged in LDS (pad-8, conflict-light) ----------------
template<int KSTEPS, int KREAL, bool ABF16, bool FUSE, bool STATS>
__global__ __launch_bounds__(256, 4) void gemm_kernel(
    const void* __restrict__ Ap, const short* __restrict__ Wt,
    const float* __restrict__ al, const float* __restrict__ be,
    short* __restrict__ C, float* __restrict__ psOut, float* __restrict__ pqOut)
{
    constexpr int KP  = KSTEPS * 32;
    constexpr int LDK = KP + 8;                 // 272B row stride -> banks spread
    constexpr int CH  = KP / 8;                 // 16B chunks per row
    __shared__ short lw[DH * LDK];
    __shared__ float sS[DH], sQ[DH];
    int tid = threadIdx.x;
    if constexpr (STATS) {
        if (tid < DH) { sS[tid] = 0.f; sQ[tid] = 0.f; }
    }
    // stage Wt (bf16, pre-converted) into LDS: vector 16B copies, full MLP
    #pragma unroll 2
    for (int idx = tid; idx < DH * CH; idx += 256) {
        int r = idx / CH, c = idx % CH;
        *(bf16x8*)&lw[r * LDK + c * 8] = *(const bf16x8*)&Wt[r * KP + c * 8];
    }
    __syncthreads();

    int wave = tid >> 6, lane = tid & 63;
    int lr = lane & 15, lk = lane >> 4;
    int row  = blockIdx.x * 64 + wave * 16 + lr;
    int ksub = lk * 8;
    bool rok = row < NNODE;

    f32x4 acc[8];
    #pragma unroll
    for (int n = 0; n < 8; ++n) acc[n] = (f32x4){0.f, 0.f, 0.f, 0.f};

    if constexpr (ABF16) {
        bf16x8 araw[KSTEPS];
        #pragma unroll
        for (int kk = 0; kk < KSTEPS; ++kk) {
            if (rok) araw[kk] = *(const bf16x8*)((const short*)Ap + (size_t)row * KREAL + kk * 32 + ksub);
            else     araw[kk] = (bf16x8){0,0,0,0,0,0,0,0};
        }
        #pragma unroll
        for (int kk = 0; kk < KSTEPS; ++kk) {
            int k0 = kk * 32 + ksub;
            union { bf16x8 v; unsigned u[4]; } raw; raw.v = araw[kk];
            float va[8];
            #pragma unroll
            for (int e = 0; e < 4; ++e) { va[2*e] = bflo(raw.u[e]); va[2*e+1] = bfhi(raw.u[e]); }
            if constexpr (FUSE) {
                const float4* ap = (const float4*)(al + k0);
                const float4* bp = (const float4*)(be + k0);
                float4 A0 = ap[0], A1 = ap[1], B0 = bp[0], B1 = bp[1];
                va[0]=fmaxf(A0.x*va[0]+B0.x,0.f); va[1]=fmaxf(A0.y*va[1]+B0.y,0.f);
                va[2]=fmaxf(A0.z*va[2]+B0.z,0.f); va[3]=fmaxf(A0.w*va[3]+B0.w,0.f);
                va[4]=fmaxf(A1.x*va[4]+B1.x,0.f); va[5]=fmaxf(A1.y*va[5]+B1.y,0.f);
                va[6]=fmaxf(A1.z*va[6]+B1.z,0.f); va[7]=fmaxf(A1.w*va[7]+B1.w,0.f);
            }
            union { bf16x8 v; unsigned u[4]; } a;
            #pragma unroll
            for (int e = 0; e < 4; ++e) a.u[e] = pkbf(va[2*e], va[2*e+1]);
            #pragma unroll
            for (int n = 0; n < 8; ++n) {
                bf16x8 bfrag = *(const bf16x8*)&lw[(n * 16 + lr) * LDK + kk * 32 + ksub];
                acc[n] = __builtin_amdgcn_mfma_f32_16x16x32_bf16(a.v, bfrag, acc[n], 0, 0, 0);
            }
        }
    } else {
        const float* arow = (const float*)Ap + (size_t)row * KREAL;
        float4 c0, c1, n0, n1;
        bool v0 = rok && (ksub + 8 <= KREAL);
        if (v0) { const float4* p = (const float4*)(arow + ksub); c0 = p[0]; c1 = p[1]; }
        else    { c0 = float4{0,0,0,0}; c1 = float4{0,0,0,0}; }
        #pragma unroll
        for (int kk = 0; kk < KSTEPS; ++kk) {
            if (kk + 1 < KSTEPS) {
                int k1 = (kk + 1) * 32 + ksub;
                bool vn = rok && (k1 + 8 <= KREAL);
                if (vn) { const float4* p = (const float4*)(arow + k1); n0 = p[0]; n1 = p[1]; }
                else    { n0 = float4{0,0,0,0}; n1 = float4{0,0,0,0}; }
            }
            float va[8];
            va[0]=c0.x; va[1]=c0.y; va[2]=c0.z; va[3]=c0.w;
            va[4]=c1.x; va[5]=c1.y; va[6]=c1.z; va[7]=c1.w;
            union { bf16x8 v; unsigned u[4]; } a;
            #pragma unroll
            for (int e = 0; e < 4; ++e) a.u[e] = pkbf(va[2*e], va[2*e+1]);
            #pragma unroll
            for (int n = 0; n < 8; ++n) {
                bf16x8 bfrag = *(const bf16x8*)&lw[(n * 16 + lr) * LDK + kk * 32 + ksub];
                acc[n] = __builtin_amdgcn_mfma_f32_16x16x32_bf16(a.v, bfrag, acc[n], 0, 0, 0);
            }
            c0 = n0; c1 = n1;
        }
    }

    int orow = blockIdx.x * 64 + wave * 16 + lk * 4;
    #pragma unroll
    for (int n = 0; n < 8; ++n) {
        #pragma unroll
        for (int j = 0; j < 4; ++j) {
            int rr = orow + j;
            if (rr < NNODE) C[(size_t)rr * DH + n * 16 + lr] = f2bf(acc[n][j]);
        }
    }

    if constexpr (STATS) {
        #pragma unroll
        for (int n = 0; n < 8; ++n) {
            float sv = 0.f, qv = 0.f;
            #pragma unroll
            for (int j = 0; j < 4; ++j) {
                if (orow + j < NNODE) { float v = acc[n][j]; sv += v; qv += v * v; }
            }
            atomicAdd(&sS[n * 16 + lr], sv);
            atomicAdd(&sQ[n * 16 + lr], qv);
        }
        __syncthreads();
        if (tid < DH) {
            int slot = (blockIdx.x & (NSLOT - 1)) * DH + tid;
            atomicAdd(&psOut[slot], sS[tid]); atomicAdd(&pqOut[slot], sQ[tid]);
        }
    }
}

// ---------------- aggregation: z = Adj@y + (1+eps)*y, bf16 in/out, NO stats, NT z-store ----------------
__global__ __launch_bounds__(256) void agg_kernel(
    const short* __restrict__ yb, short* __restrict__ zb,
    const int* __restrict__ off, const unsigned short* __restrict__ ccol,
    const float* __restrict__ epsv, int layer)
{
    int tid = threadIdx.x;
    int wave = tid >> 6, t = tid & 63;
    int node = blockIdx.x * 4 + wave;
    if (node >= NNODE) return;
    const unsigned* y2 = (const unsigned*)yb;
    int k = off[node], k1 = off[node + 1];
    float s0=0,s1=0,t0=0,t1=0,u0=0,u1=0,v0=0,v1=0;
    for (; k + 7 < k1; k += 8) {
        int c0 = ccol[k],   c1 = ccol[k+1], c2 = ccol[k+2], c3 = ccol[k+3];
        int c4 = ccol[k+4], c5 = ccol[k+5], c6 = ccol[k+6], c7 = ccol[k+7];
        unsigned a = y2[(size_t)c0 * 64 + t];
        unsigned b = y2[(size_t)c1 * 64 + t];
        unsigned c = y2[(size_t)c2 * 64 + t];
        unsigned d = y2[(size_t)c3 * 64 + t];
        unsigned e = y2[(size_t)c4 * 64 + t];
        unsigned f = y2[(size_t)c5 * 64 + t];
        unsigned g = y2[(size_t)c6 * 64 + t];
        unsigned h = y2[(size_t)c7 * 64 + t];
        s0 += bflo(a) + bflo(e); s1 += bfhi(a) + bfhi(e);
        t0 += bflo(b) + bflo(f); t1 += bfhi(b) + bfhi(f);
        u0 += bflo(c) + bflo(g); u1 += bfhi(c) + bfhi(g);
        v0 += bflo(d) + bflo(h); v1 += bfhi(d) + bfhi(h);
    }
    for (; k + 3 < k1; k += 4) {
        int c0 = ccol[k], c1 = ccol[k+1], c2 = ccol[k+2], c3 = ccol[k+3];
        unsigned a = y2[(size_t)c0 * 64 + t];
        unsigned b = y2[(size_t)c1 * 64 + t];
        unsigned c = y2[(size_t)c2 * 64 + t];
        unsigned d = y2[(size_t)c3 * 64 + t];
        s0 += bflo(a); s1 += bfhi(a); t0 += bflo(b); t1 += bfhi(b);
        u0 += bflo(c); u1 += bfhi(c); v0 += bflo(d); v1 += bfhi(d);
    }
    for (; k < k1; ++k) {
        unsigned a = y2[(size_t)ccol[k] * 64 + t];
        s0 += bflo(a); s1 += bfhi(a);
    }
    unsigned sv = y2[(size_t)node * 64 + t];
    float e = 1.f + epsv[layer];
    float rx = (s0 + t0) + (u0 + v0) + e * bflo(sv);
    float ry = (s1 + t1) + (u1 + v1) + e * bfhi(sv);
    __builtin_nontemporal_store(pkbf(rx, ry), (unsigned*)zb + (size_t)node * 64 + t);
}

// ---------------- Z BN stats (separate pass, vectorized) ----------------
__global__ __launch_bounds__(256) void statsZ_kernel(const short* __restrict__ zb,
                                                     float* __restrict__ ps, float* __restrict__ pq) {
    __shared__ float red[4][DH];
    int t = threadIdx.x;
    int cg = t & 63, rg = t >> 6;
    const unsigned* z2 = (const unsigned*)zb;
    int r0 = blockIdx.x * 196, r1 = min(r0 + 196, NNODE);
    float s0 = 0.f, s1 = 0.f, q0 = 0.f, q1 = 0.f;
    for (int r = r0 + rg; r < r1; r += 4) {
        unsigned v = z2[(size_t)r * 64 + cg];
        float a = bflo(v), b = bfhi(v);
        s0 += a; q0 += a * a; s1 += b; q1 += b * b;
    }
    red[rg][2 * cg] = s0; red[rg][2 * cg + 1] = s1;
    __syncthreads();
    if (t < DH) {
        float s = red[0][t] + red[1][t] + red[2][t] + red[3][t];
        atomicAdd(&ps[(blockIdx.x & (NSLOT - 1)) * DH + t], s);
    }
    __syncthreads();
    red[rg][2 * cg] = q0; red[rg][2 * cg + 1] = q1;
    __syncthreads();
    if (t < DH) {
        float q = red[0][t] + red[1][t] + red[2][t] + red[3][t];
        atomicAdd(&pq[(blockIdx.x & (NSLOT - 1)) * DH + t], q);
    }
}

// ---------------- pooling ----------------
__global__ __launch_bounds__(256) void poolx_kernel(const float* __restrict__ x,
                                                    const int* __restrict__ gs, float* __restrict__ out) {
    int g = blockIdx.x >> 4, sp = blockIdx.x & 15, t = threadIdx.x;
    if (t >= DIN) return;
    int lo = gs[g], hi = gs[g + 1], len = hi - lo;
    int r0 = lo + (len * sp >> 4), r1 = lo + (len * (sp + 1) >> 4);
    float a0 = 0.f, a1 = 0.f;
    int r = r0;
    for (; r + 1 < r1; r += 2) {
        a0 += x[(size_t)r * DIN + t];
        a1 += x[(size_t)(r + 1) * DIN + t];
    }
    if (r < r1) a0 += x[(size_t)r * DIN + t];
    atomicAdd(&out[g * OUTW + t], a0 + a1);
}

__global__ __launch_bounds__(128) void pool_kernel(const short* __restrict__ rep,
                                                   const float* __restrict__ al, const float* __restrict__ be,
                                                   const int* __restrict__ gs, float* __restrict__ out, int ooff) {
    int c = threadIdx.x;
    float a = al[c], b = be[c];
    int g = blockIdx.x >> 3, sp = blockIdx.x & 7;
    int lo = gs[g], hi = gs[g + 1], len = hi - lo;
    int r0 = lo + (len * sp >> 3), r1 = lo + (len * (sp + 1) >> 3);
    float acc = 0.f;
    const unsigned short* rp = (const unsigned short*)rep;
    for (int r = r0; r < r1; ++r) acc += fmaxf(a * bfs(rp[(size_t)r * DH + c]) + b, 0.f);
    atomicAdd(&out[g * OUTW + ooff + c], acc);
}

// ---------------- launch ----------------
extern "C" void kernel_launch(void* const* d_in, const int* in_sizes, int n_in,
                              void* d_out, int out_size, void* d_ws, size_t ws_size,
                              hipStream_t stream)
{
    const float* x    = (const float*)d_in[0];
    const int*   erow = (const int*)d_in[1];
    const int*   ecol = (const int*)d_in[2];
    const int*   gid  = (const int*)d_in[3];
    const float* eps  = (const float*)d_in[4];
    const float* w1_0 = (const float*)d_in[5];
    const float* g1_0 = (const float*)d_in[7];
    const float* be10 = (const float*)d_in[8];
    const float* w2_0 = (const float*)d_in[9];
    const float* gbn0 = (const float*)d_in[11];
    const float* bbn0 = (const float*)d_in[12];
    const float* w1_r = (const float*)d_in[13];
    const float* g1_r = (const float*)d_in[15];
    const float* be1r = (const float*)d_in[16];
    const float* w2_r = (const float*)d_in[17];
    const float* gbnr = (const float*)d_in[19];
    const float* bbnr = (const float*)d_in[20];
    float* out = (float*)d_out;

    // workspace layout
    short* Zb = (short*)d_ws;                       // NNODE*DH bf16
    short* Y  = Zb + (size_t)NNODE * DH;
    short* RA = Y  + (size_t)NNODE * DH;
    short* RB = RA + (size_t)NNODE * DH;
    short* Wt = RB + (size_t)NNODE * DH;            // 143360 shorts
    float* stats = (float*)(Wt + 143360);           // 4 layers * 4 * NSLOT*DH = 65536 floats
    float* a1v = stats + 65536;                     // BN param buffers
    float* b1v = a1v + DH;
    float* a2v = b1v + DH;
    float* b2v = a2v + DH;
    int* bcnt = (int*)(b2v + DH);                   // 256
    int* boff = bcnt + 256;
    int* bcur = boff + 256;
    int* off  = bcur + 256;                         // 50016
    unsigned* bdata = (unsigned*)(off + 50016);     // NEDGE
    unsigned short* ccol = (unsigned short*)(bdata + NEDGE);  // NEDGE u16
    int* gs = (int*)(ccol + NEDGE);                 // 129

    prezero_kernel<<<1, 256, 0, stream>>>(bcnt);
    setup_kernel<<<2292, 256, 0, stream>>>(out, stats, bcnt, gid, gs,
                                           w1_0, w2_0, w1_r, w2_r, Wt, erow);
    scanB_kernel<<<1, 256, 0, stream>>>(bcnt, boff, bcur, off);
    scatterA_kernel<<<782, 256, 0, stream>>>(erow, ecol, boff, bcur, bdata);
    bucketB_kernel<<<NB, 256, 0, stream>>>(bdata, boff, off, ccol);
    poolx_kernel<<<NGRAPH * 16, 256, 0, stream>>>(x, gs, out);

    const int GB = (NNODE + 63) / 64;   // 782
    const int LS = NSLOT * DH;
    for (int l = 0; l < 4; ++l) {
        const short* Wt1 = (l == 0) ? Wt : Wt + 28672 + (size_t)(2 * l - 1) * 16384;
        const short* Wt2 = (l == 0) ? Wt + 28672 : Wt + 28672 + (size_t)(2 * l) * 16384;
        const float* G1 = (l == 0) ? g1_0 : (g1_r + (l - 1) * DH);
        const float* B1 = (l == 0) ? be10 : (be1r + (l - 1) * DH);
        const float* G2 = (l == 0) ? gbn0 : (gbnr + (l - 1) * DH);
        const float* B2 = (l == 0) ? bbn0 : (bbnr + (l - 1) * DH);
        short* rep = (l & 1) ? RB : RA;
        float* psZ = stats + l * 4 * LS;
        float* pqZ = psZ + LS;
        float* psA = pqZ + LS;
        float* pqA = psA + LS;

        if (l == 0)
            gemm_kernel<7, 200, false, false, false><<<GB, 256, 0, stream>>>(
                x, Wt1, nullptr, nullptr, Y, nullptr, nullptr);
        else {
            const short* prev = ((l - 1) & 1) ? RB : RA;
            gemm_kernel<4, 128, true, true, false><<<GB, 256, 0, stream>>>(
                prev, Wt1, a2v, b2v, Y, nullptr, nullptr);
        }
        agg_kernel<<<(NNODE + 3) / 4, 256, 0, stream>>>(Y, Zb, off, ccol, eps, l);
        statsZ_kernel<<<256, 256, 0, stream>>>(Zb, psZ, pqZ);
        colparams_kernel<<<1, 128, 0, stream>>>(psZ, pqZ, G1, B1, a1v, b1v);
        gemm_kernel<4, 128, true, true, true><<<GB, 256, 0, stream>>>(
            Zb, Wt2, a1v, b1v, rep, psA, pqA);
        colparams_kernel<<<1, 128, 0, stream>>>(psA, pqA, G2, B2, a2v, b2v);
        pool_kernel<<<NGRAPH * 8, 128, 0, stream>>>(rep, a2v, b2v, gs, out, DIN + l * DH);
    }
}

// Round 14
// 537.466 us; speedup vs baseline: 1.1807x; 1.0144x over previous
//
#include <hip/hip_runtime.h>
#include <hip/hip_bf16.h>

#define NNODE 50000
#define NEDGE 800000
#define NGRAPH 128
#define DIN 200
#define DH 128
#define OUTW (DIN + 4*DH)   // 712
#define NB 196              // node buckets of 256 rows
#define NSLOT 32            // stat partial slots

typedef short bf16x8 __attribute__((ext_vector_type(8)));
typedef float f32x4  __attribute__((ext_vector_type(4)));

__device__ __forceinline__ short f2bf(float f) {
    union { float f; unsigned u; } x; x.f = f;
    unsigned u = x.u;
    u += 0x7fffu + ((u >> 16) & 1u);   // RNE
    return (short)(u >> 16);
}
__device__ __forceinline__ float bflo(unsigned v) {
    union { unsigned u; float f; } x; x.u = v << 16; return x.f;
}
__device__ __forceinline__ float bfhi(unsigned v) {
    union { unsigned u; float f; } x; x.u = v & 0xffff0000u; return x.f;
}
__device__ __forceinline__ float bfs(unsigned short v) {
    union { unsigned u; float f; } x; x.u = ((unsigned)v) << 16; return x.f;
}
__device__ __forceinline__ unsigned pkbf(float lo, float hi) {
    __hip_bfloat162 p = __float22bfloat162_rn(float2{lo, hi});
    unsigned u; __builtin_memcpy(&u, &p, 4); return u;
}

// ---------------- pre-zero: bcnt must be zero BEFORE the setup dispatch that histograms into it
__global__ __launch_bounds__(256) void prezero_kernel(int* __restrict__ bcnt) {
    bcnt[threadIdx.x] = 0;
}

// ---------------- mega-setup: zero out/stats, gs bounds, wconv, histB ----------------
__global__ __launch_bounds__(256) void setup_kernel(
    float* __restrict__ out, float* __restrict__ statz, int* __restrict__ bcnt,
    const int* __restrict__ gid, int* __restrict__ gs,
    const float* __restrict__ w1_0, const float* __restrict__ w2_0,
    const float* __restrict__ w1_r, const float* __restrict__ w2_r, short* __restrict__ Wt,
    const int* __restrict__ erow)
{
    __shared__ int lh[224];
    int b = blockIdx.x, t = threadIdx.x;
    if (b < 356) {                       // zero ALL of out: 712*128 = 91136 = 356*256
        out[b * 256 + t] = 0.f;
    } else if (b < 612) {                // stats: 4 layers * 4 arrays * 32*128 = 65536 floats
        statz[(b - 356) * 256 + t] = 0.f;
    } else if (b == 612) {
        // (bcnt zeroing in prezero_kernel -- intra-dispatch race fix)
    } else if (b == 613) {
        if (t <= NGRAPH) {
            int lo = 0, hi = NNODE;
            while (lo < hi) { int m = (lo + hi) >> 1; if (gid[m] < t) lo = m + 1; else hi = m; }
            gs[t] = lo;
        }
    } else if (b < 614 + 896) {          // wconv: 8 matrices
        int wb = b - 614;
        int m = wb / 112, sub = wb % 112;
        int idx = sub * 256 + t;
        int KP = (m == 0) ? 224 : 128;
        if (idx < KP * DH) {
            int k = idx >> 7, c = idx & 127;
            const float* src = (m == 0) ? w1_0 : (m == 1) ? w2_0
                             : ((m & 1) == 0 ? w1_r + (size_t)((m - 2) >> 1) * DH * DH
                                             : w2_r + (size_t)((m - 3) >> 1) * DH * DH);
            int KREAL = (m == 0) ? 200 : 128;
            float v = (k < KREAL) ? src[k * DH + c] : 0.f;
            short* dst = Wt + ((m == 0) ? 0 : 28672 + (m - 1) * 16384);
            dst[c * KP + k] = f2bf(v);
        }
    } else {                             // histB: 782 blocks
        int hb = b - 1510;
        if (t < 224) lh[t] = 0;
        __syncthreads();
        int base = hb * 1024;
        #pragma unroll
        for (int i = 0; i < 4; ++i) {
            int e = base + i * 256 + t;
            if (e < NEDGE) atomicAdd(&lh[erow[e] >> 8], 1);
        }
        __syncthreads();
        if (t < NB && lh[t]) atomicAdd(&bcnt[t], lh[t]);
    }
}

// ---------------- CSR build ----------------
__global__ __launch_bounds__(256) void scanB_kernel(const int* __restrict__ bcnt, int* __restrict__ boff,
                                                    int* __restrict__ bcur, int* __restrict__ off) {
    __shared__ int sd[256];
    int t = threadIdx.x;
    int v = (t < NB) ? bcnt[t] : 0;
    sd[t] = v; __syncthreads();
    for (int s = 1; s < 256; s <<= 1) {
        int x = (t >= s) ? sd[t - s] : 0;
        __syncthreads(); sd[t] += x; __syncthreads();
    }
    if (t < NB) { boff[t] = sd[t] - v; bcur[t] = 0; }
    if (t == 0) { boff[NB] = NEDGE; off[NNODE] = NEDGE; }
}

__global__ __launch_bounds__(256) void scatterA_kernel(const int* __restrict__ erow, const int* __restrict__ ecol,
                                                       const int* __restrict__ boff, int* __restrict__ bcur,
                                                       unsigned* __restrict__ bdata) {
    __shared__ int lh[224], gb[224];
    int t = threadIdx.x;
    if (t < 224) lh[t] = 0;
    __syncthreads();
    int base = blockIdx.x * 1024;
    int bb[4], rk[4]; unsigned pk[4];
    #pragma unroll
    for (int i = 0; i < 4; ++i) {
        int e = base + i * 256 + t;
        if (e < NEDGE) {
            int r = erow[e];
            bb[i] = r >> 8;
            pk[i] = ((unsigned)(r & 255) << 16) | (unsigned)ecol[e];
            rk[i] = atomicAdd(&lh[bb[i]], 1);
        } else bb[i] = -1;
    }
    __syncthreads();
    if (t < NB && lh[t] > 0) gb[t] = atomicAdd(&bcur[t], lh[t]);
    __syncthreads();
    #pragma unroll
    for (int i = 0; i < 4; ++i) {
        if (bb[i] >= 0) bdata[boff[bb[i]] + gb[bb[i]] + rk[i]] = pk[i];
    }
}

__global__ __launch_bounds__(256) void bucketB_kernel(const unsigned* __restrict__ bdata, const int* __restrict__ boff,
                                                      int* __restrict__ off, unsigned short* __restrict__ ccol) {
    __shared__ int lh[256], loff[256], lcur[256];
    int b = blockIdx.x, t = threadIdx.x;
    lh[t] = 0; lcur[t] = 0;
    __syncthreads();
    int lo = boff[b], hi = boff[b + 1];
    for (int e = lo + t; e < hi; e += 256) atomicAdd(&lh[bdata[e] >> 16], 1);
    __syncthreads();
    loff[t] = lh[t]; __syncthreads();
    for (int s = 1; s < 256; s <<= 1) {
        int x = (t >= s) ? loff[t - s] : 0;
        __syncthreads(); loff[t] += x; __syncthreads();
    }
    int row = b * 256 + t;
    if (row < NNODE) off[row] = lo + loff[t] - lh[t];
    __syncthreads();
    for (int e = lo + t; e < hi; e += 256) {
        unsigned v = bdata[e];
        int rlo = v >> 16;
        int p = atomicAdd(&lcur[rlo], 1);
        ccol[lo + loff[rlo] - lh[rlo] + p] = (unsigned short)(v & 0xffffu);
    }
}

// ---------------- GEMM: C[NNODE][128] = act(A) @ W; LDS-staged B + in-prologue BN params ----------------
template<int KSTEPS, int KREAL, bool ABF16, bool FUSE, bool STATS>
__global__ __launch_bounds__(256, 4) void gemm_kernel(
    const void* __restrict__ Ap, const short* __restrict__ Wt,
    const float* __restrict__ psIn, const float* __restrict__ pqIn,
    const float* __restrict__ gammaIn, const float* __restrict__ betaIn,
    short* __restrict__ C, float* __restrict__ psOut, float* __restrict__ pqOut)
{
    constexpr int KP  = KSTEPS * 32;
    constexpr int LDK = KP + 8;                 // 272B row stride -> banks spread
    constexpr int CH  = KP / 8;                 // 16B chunks per row
    __shared__ short lw[DH * LDK];
    __shared__ float lal[DH], lbe[DH], sS[DH], sQ[DH];
    int tid = threadIdx.x;
    if constexpr (FUSE) {
        if (tid < DH) {
            float s = 0.f, q = 0.f;
            #pragma unroll 8
            for (int i = 0; i < NSLOT; ++i) { s += psIn[i * DH + tid]; q += pqIn[i * DH + tid]; }
            float mean = s * (1.f / NNODE);
            float var  = fmaxf(q * (1.f / NNODE) - mean * mean, 0.f);
            float a    = gammaIn[tid] * rsqrtf(var + 1e-5f);
            lal[tid] = a; lbe[tid] = betaIn[tid] - a * mean;
        }
    }
    if constexpr (STATS) {
        if (tid < DH) { sS[tid] = 0.f; sQ[tid] = 0.f; }
    }
    // stage Wt (bf16, pre-converted) into LDS: vector 16B copies, full MLP
    #pragma unroll 2
    for (int idx = tid; idx < DH * CH; idx += 256) {
        int r = idx / CH, c = idx % CH;
        *(bf16x8*)&lw[r * LDK + c * 8] = *(const bf16x8*)&Wt[r * KP + c * 8];
    }
    __syncthreads();

    int wave = tid >> 6, lane = tid & 63;
    int lr = lane & 15, lk = lane >> 4;
    int row  = blockIdx.x * 64 + wave * 16 + lr;
    int ksub = lk * 8;
    bool rok = row < NNODE;

    f32x4 acc[8];
    #pragma unroll
    for (int n = 0; n < 8; ++n) acc[n] = (f32x4){0.f, 0.f, 0.f, 0.f};

    if constexpr (ABF16) {
        bf16x8 araw[KSTEPS];
        #pragma unroll
        for (int kk = 0; kk < KSTEPS; ++kk) {
            if (rok) araw[kk] = *(const bf16x8*)((const short*)Ap + (size_t)row * KREAL + kk * 32 + ksub);
            else     araw[kk] = (bf16x8){0,0,0,0,0,0,0,0};
        }
        #pragma unroll
        for (int kk = 0; kk < KSTEPS; ++kk) {
            int k0 = kk * 32 + ksub;
            union { bf16x8 v; unsigned u[4]; } raw; raw.v = araw[kk];
            float va[8];
            #pragma unroll
            for (int e = 0; e < 4; ++e) { va[2*e] = bflo(raw.u[e]); va[2*e+1] = bfhi(raw.u[e]); }
            if constexpr (FUSE) {
                #pragma unroll
                for (int e = 0; e < 8; ++e)
                    va[e] = fmaxf(lal[k0 + e] * va[e] + lbe[k0 + e], 0.f);
            }
            union { bf16x8 v; unsigned u[4]; } a;
            #pragma unroll
            for (int e = 0; e < 4; ++e) a.u[e] = pkbf(va[2*e], va[2*e+1]);
            #pragma unroll
            for (int n = 0; n < 8; ++n) {
                bf16x8 bfrag = *(const bf16x8*)&lw[(n * 16 + lr) * LDK + kk * 32 + ksub];
                acc[n] = __builtin_amdgcn_mfma_f32_16x16x32_bf16(a.v, bfrag, acc[n], 0, 0, 0);
            }
        }
    } else {
        const float* arow = (const float*)Ap + (size_t)row * KREAL;
        float4 c0, c1, n0, n1;
        bool v0 = rok && (ksub + 8 <= KREAL);
        if (v0) { const float4* p = (const float4*)(arow + ksub); c0 = p[0]; c1 = p[1]; }
        else    { c0 = float4{0,0,0,0}; c1 = float4{0,0,0,0}; }
        #pragma unroll
        for (int kk = 0; kk < KSTEPS; ++kk) {
            if (kk + 1 < KSTEPS) {
                int k1 = (kk + 1) * 32 + ksub;
                bool vn = rok && (k1 + 8 <= KREAL);
                if (vn) { const float4* p = (const float4*)(arow + k1); n0 = p[0]; n1 = p[1]; }
                else    { n0 = float4{0,0,0,0}; n1 = float4{0,0,0,0}; }
            }
            float va[8];
            va[0]=c0.x; va[1]=c0.y; va[2]=c0.z; va[3]=c0.w;
            va[4]=c1.x; va[5]=c1.y; va[6]=c1.z; va[7]=c1.w;
            union { bf16x8 v; unsigned u[4]; } a;
            #pragma unroll
            for (int e = 0; e < 4; ++e) a.u[e] = pkbf(va[2*e], va[2*e+1]);
            #pragma unroll
            for (int n = 0; n < 8; ++n) {
                bf16x8 bfrag = *(const bf16x8*)&lw[(n * 16 + lr) * LDK + kk * 32 + ksub];
                acc[n] = __builtin_amdgcn_mfma_f32_16x16x32_bf16(a.v, bfrag, acc[n], 0, 0, 0);
            }
            c0 = n0; c1 = n1;
        }
    }

    int orow = blockIdx.x * 64 + wave * 16 + lk * 4;
    #pragma unroll
    for (int n = 0; n < 8; ++n) {
        #pragma unroll
        for (int j = 0; j < 4; ++j) {
            int rr = orow + j;
            if (rr < NNODE) C[(size_t)rr * DH + n * 16 + lr] = f2bf(acc[n][j]);
        }
    }

    if constexpr (STATS) {
        #pragma unroll
        for (int n = 0; n < 8; ++n) {
            float sv = 0.f, qv = 0.f;
            #pragma unroll
            for (int j = 0; j < 4; ++j) {
                if (orow + j < NNODE) { float v = acc[n][j]; sv += v; qv += v * v; }
            }
            atomicAdd(&sS[n * 16 + lr], sv);
            atomicAdd(&sQ[n * 16 + lr], qv);
        }
        __syncthreads();
        if (tid < DH) {
            int slot = (blockIdx.x & (NSLOT - 1)) * DH + tid;
            atomicAdd(&psOut[slot], sS[tid]); atomicAdd(&pqOut[slot], sQ[tid]);
        }
    }
}

// ---------------- aggregation: z = Adj@y + (1+eps)*y, bf16 in/out, NO stats, NT z-store ----------------
__global__ __launch_bounds__(256) void agg_kernel(
    const short* __restrict__ yb, short* __restrict__ zb,
    const int* __restrict__ off, const unsigned short* __restrict__ ccol,
    const float* __restrict__ epsv, int layer)
{
    int tid = threadIdx.x;
    int wave = tid >> 6, t = tid & 63;
    int node = blockIdx.x * 4 + wave;
    if (node >= NNODE) return;
    const unsigned* y2 = (const unsigned*)yb;
    int k = off[node], k1 = off[node + 1];
    float s0=0,s1=0,t0=0,t1=0,u0=0,u1=0,v0=0,v1=0;
    for (; k + 7 < k1; k += 8) {
        int c0 = ccol[k],   c1 = ccol[k+1], c2 = ccol[k+2], c3 = ccol[k+3];
        int c4 = ccol[k+4], c5 = ccol[k+5], c6 = ccol[k+6], c7 = ccol[k+7];
        unsigned a = y2[(size_t)c0 * 64 + t];
        unsigned b = y2[(size_t)c1 * 64 + t];
        unsigned c = y2[(size_t)c2 * 64 + t];
        unsigned d = y2[(size_t)c3 * 64 + t];
        unsigned e = y2[(size_t)c4 * 64 + t];
        unsigned f = y2[(size_t)c5 * 64 + t];
        unsigned g = y2[(size_t)c6 * 64 + t];
        unsigned h = y2[(size_t)c7 * 64 + t];
        s0 += bflo(a) + bflo(e); s1 += bfhi(a) + bfhi(e);
        t0 += bflo(b) + bflo(f); t1 += bfhi(b) + bfhi(f);
        u0 += bflo(c) + bflo(g); u1 += bfhi(c) + bfhi(g);
        v0 += bflo(d) + bflo(h); v1 += bfhi(d) + bfhi(h);
    }
    for (; k + 3 < k1; k += 4) {
        int c0 = ccol[k], c1 = ccol[k+1], c2 = ccol[k+2], c3 = ccol[k+3];
        unsigned a = y2[(size_t)c0 * 64 + t];
        unsigned b = y2[(size_t)c1 * 64 + t];
        unsigned c = y2[(size_t)c2 * 64 + t];
        unsigned d = y2[(size_t)c3 * 64 + t];
        s0 += bflo(a); s1 += bfhi(a); t0 += bflo(b); t1 += bfhi(b);
        u0 += bflo(c); u1 += bfhi(c); v0 += bflo(d); v1 += bfhi(d);
    }
    for (; k < k1; ++k) {
        unsigned a = y2[(size_t)ccol[k] * 64 + t];
        s0 += bflo(a); s1 += bfhi(a);
    }
    unsigned sv = y2[(size_t)node * 64 + t];
    float e = 1.f + epsv[layer];
    float rx = (s0 + t0) + (u0 + v0) + e * bflo(sv);
    float ry = (s1 + t1) + (u1 + v1) + e * bfhi(sv);
    __builtin_nontemporal_store(pkbf(rx, ry), (unsigned*)zb + (size_t)node * 64 + t);
}

// ---------------- Z BN stats (separate pass, vectorized) ----------------
__global__ __launch_bounds__(256) void statsZ_kernel(const short* __restrict__ zb,
                                                     float* __restrict__ ps, float* __restrict__ pq) {
    __shared__ float red[4][DH];
    int t = threadIdx.x;
    int cg = t & 63, rg = t >> 6;
    const unsigned* z2 = (const unsigned*)zb;
    int r0 = blockIdx.x * 196, r1 = min(r0 + 196, NNODE);
    float s0 = 0.f, s1 = 0.f, q0 = 0.f, q1 = 0.f;
    for (int r = r0 + rg; r < r1; r += 4) {
        unsigned v = z2[(size_t)r * 64 + cg];
        float a = bflo(v), b = bfhi(v);
        s0 += a; q0 += a * a; s1 += b; q1 += b * b;
    }
    red[rg][2 * cg] = s0; red[rg][2 * cg + 1] = s1;
    __syncthreads();
    if (t < DH) {
        float s = red[0][t] + red[1][t] + red[2][t] + red[3][t];
        atomicAdd(&ps[(blockIdx.x & (NSLOT - 1)) * DH + t], s);
    }
    __syncthreads();
    red[rg][2 * cg] = q0; red[rg][2 * cg + 1] = q1;
    __syncthreads();
    if (t < DH) {
        float q = red[0][t] + red[1][t] + red[2][t] + red[3][t];
        atomicAdd(&pq[(blockIdx.x & (NSLOT - 1)) * DH + t], q);
    }
}

// ---------------- pooling ----------------
__global__ __launch_bounds__(256) void poolx_kernel(const float* __restrict__ x,
                                                    const int* __restrict__ gs, float* __restrict__ out) {
    int g = blockIdx.x >> 4, sp = blockIdx.x & 15, t = threadIdx.x;
    if (t >= DIN) return;
    int lo = gs[g], hi = gs[g + 1], len = hi - lo;
    int r0 = lo + (len * sp >> 4), r1 = lo + (len * (sp + 1) >> 4);
    float a0 = 0.f, a1 = 0.f;
    int r = r0;
    for (; r + 1 < r1; r += 2) {
        a0 += x[(size_t)r * DIN + t];
        a1 += x[(size_t)(r + 1) * DIN + t];
    }
    if (r < r1) a0 += x[(size_t)r * DIN + t];
    atomicAdd(&out[g * OUTW + t], a0 + a1);
}

__global__ __launch_bounds__(128) void pool_kernel(const short* __restrict__ rep,
                                                   const float* __restrict__ psIn, const float* __restrict__ pqIn,
                                                   const float* __restrict__ gammaIn, const float* __restrict__ betaIn,
                                                   const int* __restrict__ gs, float* __restrict__ out, int ooff) {
    int c = threadIdx.x;
    float s = 0.f, q = 0.f;
    #pragma unroll 8
    for (int i = 0; i < NSLOT; ++i) { s += psIn[i * DH + c]; q += pqIn[i * DH + c]; }
    float mean = s * (1.f / NNODE);
    float var  = fmaxf(q * (1.f / NNODE) - mean * mean, 0.f);
    float a    = gammaIn[c] * rsqrtf(var + 1e-5f);
    float b    = betaIn[c] - a * mean;

    int g = blockIdx.x >> 3, sp = blockIdx.x & 7;
    int lo = gs[g], hi = gs[g + 1], len = hi - lo;
    int r0 = lo + (len * sp >> 3), r1 = lo + (len * (sp + 1) >> 3);
    float acc = 0.f;
    const unsigned short* rp = (const unsigned short*)rep;
    for (int r = r0; r < r1; ++r) acc += fmaxf(a * bfs(rp[(size_t)r * DH + c]) + b, 0.f);
    atomicAdd(&out[g * OUTW + ooff + c], acc);
}

// ---------------- launch ----------------
extern "C" void kernel_launch(void* const* d_in, const int* in_sizes, int n_in,
                              void* d_out, int out_size, void* d_ws, size_t ws_size,
                              hipStream_t stream)
{
    const float* x    = (const float*)d_in[0];
    const int*   erow = (const int*)d_in[1];
    const int*   ecol = (const int*)d_in[2];
    const int*   gid  = (const int*)d_in[3];
    const float* eps  = (const float*)d_in[4];
    const float* w1_0 = (const float*)d_in[5];
    const float* g1_0 = (const float*)d_in[7];
    const float* be10 = (const float*)d_in[8];
    const float* w2_0 = (const float*)d_in[9];
    const float* gbn0 = (const float*)d_in[11];
    const float* bbn0 = (const float*)d_in[12];
    const float* w1_r = (const float*)d_in[13];
    const float* g1_r = (const float*)d_in[15];
    const float* be1r = (const float*)d_in[16];
    const float* w2_r = (const float*)d_in[17];
    const float* gbnr = (const float*)d_in[19];
    const float* bbnr = (const float*)d_in[20];
    float* out = (float*)d_out;

    // workspace layout
    short* Zb = (short*)d_ws;                       // NNODE*DH bf16
    short* Y  = Zb + (size_t)NNODE * DH;
    short* RA = Y  + (size_t)NNODE * DH;
    short* RB = RA + (size_t)NNODE * DH;
    short* Wt = RB + (size_t)NNODE * DH;            // 143360 shorts
    float* stats = (float*)(Wt + 143360);           // 4 layers * 4 * NSLOT*DH = 65536 floats
    int* bcnt = (int*)(stats + 65536);              // 256
    int* boff = bcnt + 256;
    int* bcur = boff + 256;
    int* off  = bcur + 256;                         // 50016
    unsigned* bdata = (unsigned*)(off + 50016);     // NEDGE
    unsigned short* ccol = (unsigned short*)(bdata + NEDGE);  // NEDGE u16
    int* gs = (int*)(ccol + NEDGE);                 // 129

    prezero_kernel<<<1, 256, 0, stream>>>(bcnt);
    setup_kernel<<<2292, 256, 0, stream>>>(out, stats, bcnt, gid, gs,
                                           w1_0, w2_0, w1_r, w2_r, Wt, erow);
    scanB_kernel<<<1, 256, 0, stream>>>(bcnt, boff, bcur, off);
    scatterA_kernel<<<782, 256, 0, stream>>>(erow, ecol, boff, bcur, bdata);
    bucketB_kernel<<<NB, 256, 0, stream>>>(bdata, boff, off, ccol);
    poolx_kernel<<<NGRAPH * 16, 256, 0, stream>>>(x, gs, out);

    const int GB = (NNODE + 63) / 64;   // 782
    const int LS = NSLOT * DH;
    for (int l = 0; l < 4; ++l) {
        const short* Wt1 = (l == 0) ? Wt : Wt + 28672 + (size_t)(2 * l - 1) * 16384;
        const short* Wt2 = (l == 0) ? Wt + 28672 : Wt + 28672 + (size_t)(2 * l) * 16384;
        const float* G1 = (l == 0) ? g1_0 : (g1_r + (l - 1) * DH);
        const float* B1 = (l == 0) ? be10 : (be1r + (l - 1) * DH);
        const float* G2 = (l == 0) ? gbn0 : (gbnr + (l - 1) * DH);
        const float* B2 = (l == 0) ? bbn0 : (bbnr + (l - 1) * DH);
        short* rep = (l & 1) ? RB : RA;
        float* psZ = stats + l * 4 * LS;
        float* pqZ = psZ + LS;
        float* psA = pqZ + LS;
        float* pqA = psA + LS;

        if (l == 0)
            gemm_kernel<7, 200, false, false, false><<<GB, 256, 0, stream>>>(
                x, Wt1, nullptr, nullptr, nullptr, nullptr, Y, nullptr, nullptr);
        else {
            const short* prev = ((l - 1) & 1) ? RB : RA;
            float* psAp = stats + (l - 1) * 4 * LS + 2 * LS;
            float* pqAp = psAp + LS;
            const float* G2prev = (l - 1 == 0) ? gbn0 : (gbnr + (l - 2) * DH);
            const float* B2prev = (l - 1 == 0) ? bbn0 : (bbnr + (l - 2) * DH);
            gemm_kernel<4, 128, true, true, false><<<GB, 256, 0, stream>>>(
                prev, Wt1, psAp, pqAp, G2prev, B2prev, Y, nullptr, nullptr);
        }
        agg_kernel<<<(NNODE + 3) / 4, 256, 0, stream>>>(Y, Zb, off, ccol, eps, l);
        statsZ_kernel<<<256, 256, 0, stream>>>(Zb, psZ, pqZ);
        gemm_kernel<4, 128, true, true, true><<<GB, 256, 0, stream>>>(
            Zb, Wt2, psZ, pqZ, G1, B1, rep, psA, pqA);
        pool_kernel<<<NGRAPH * 8, 128, 0, stream>>>(rep, psA, pqA, G2, B2, gs, out, DIN + l * DH);
    }
}

// Round 15
// 462.164 us; speedup vs baseline: 1.3730x; 1.1629x over previous
//
#include <hip/hip_runtime.h>
#include <hip/hip_bf16.h>

#define NNODE 50000
#define NEDGE 800000
#define NGRAPH 128
#define DIN 200
#define DH 128
#define OUTW (DIN + 4*DH)   // 712
#define NB 196              // node buckets of 256 rows
#define NSLOT 32            // stat partial slots

typedef short bf16x8 __attribute__((ext_vector_type(8)));
typedef float f32x4  __attribute__((ext_vector_type(4)));

__device__ __forceinline__ short f2bf(float f) {
    union { float f; unsigned u; } x; x.f = f;
    unsigned u = x.u;
    u += 0x7fffu + ((u >> 16) & 1u);   // RNE
    return (short)(u >> 16);
}
__device__ __forceinline__ float bflo(unsigned v) {
    union { unsigned u; float f; } x; x.u = v << 16; return x.f;
}
__device__ __forceinline__ float bfhi(unsigned v) {
    union { unsigned u; float f; } x; x.u = v & 0xffff0000u; return x.f;
}
__device__ __forceinline__ float bfs(unsigned short v) {
    union { unsigned u; float f; } x; x.u = ((unsigned)v) << 16; return x.f;
}
__device__ __forceinline__ unsigned pkbf(float lo, float hi) {
    __hip_bfloat162 p = __float22bfloat162_rn(float2{lo, hi});
    unsigned u; __builtin_memcpy(&u, &p, 4); return u;
}

// ---------------- pre-zero: bcnt must be zero BEFORE the setup dispatch that histograms into it
__global__ __launch_bounds__(256) void prezero_kernel(int* __restrict__ bcnt) {
    bcnt[threadIdx.x] = 0;
}

// ---------------- mega-setup: zero out/stats, gs bounds, wconv, histB ----------------
__global__ __launch_bounds__(256) void setup_kernel(
    float* __restrict__ out, float* __restrict__ statz, int* __restrict__ bcnt,
    const int* __restrict__ gid, int* __restrict__ gs,
    const float* __restrict__ w1_0, const float* __restrict__ w2_0,
    const float* __restrict__ w1_r, const float* __restrict__ w2_r, short* __restrict__ Wt,
    const int* __restrict__ erow)
{
    __shared__ int lh[224];
    int b = blockIdx.x, t = threadIdx.x;
    if (b < 356) {                       // zero ALL of out
        out[b * 256 + t] = 0.f;
    } else if (b < 612) {                // stats: 65536 floats
        statz[(b - 356) * 256 + t] = 0.f;
    } else if (b == 612) {
        // (bcnt zeroing in prezero_kernel -- intra-dispatch race fix)
    } else if (b == 613) {
        if (t <= NGRAPH) {
            int lo = 0, hi = NNODE;
            while (lo < hi) { int m = (lo + hi) >> 1; if (gid[m] < t) lo = m + 1; else hi = m; }
            gs[t] = lo;
        }
    } else if (b < 614 + 896) {          // wconv: 8 matrices
        int wb = b - 614;
        int m = wb / 112, sub = wb % 112;
        int idx = sub * 256 + t;
        int KP = (m == 0) ? 224 : 128;
        if (idx < KP * DH) {
            int k = idx >> 7, c = idx & 127;
            const float* src = (m == 0) ? w1_0 : (m == 1) ? w2_0
                             : ((m & 1) == 0 ? w1_r + (size_t)((m - 2) >> 1) * DH * DH
                                             : w2_r + (size_t)((m - 3) >> 1) * DH * DH);
            int KREAL = (m == 0) ? 200 : 128;
            float v = (k < KREAL) ? src[k * DH + c] : 0.f;
            short* dst = Wt + ((m == 0) ? 0 : 28672 + (m - 1) * 16384);
            dst[c * KP + k] = f2bf(v);
        }
    } else {                             // histB: 782 blocks
        int hb = b - 1510;
        if (t < 224) lh[t] = 0;
        __syncthreads();
        int base = hb * 1024;
        #pragma unroll
        for (int i = 0; i < 4; ++i) {
            int e = base + i * 256 + t;
            if (e < NEDGE) atomicAdd(&lh[erow[e] >> 8], 1);
        }
        __syncthreads();
        if (t < NB && lh[t]) atomicAdd(&bcnt[t], lh[t]);
    }
}

// ---------------- CSR build ----------------
__global__ __launch_bounds__(256) void scanB_kernel(const int* __restrict__ bcnt, int* __restrict__ boff,
                                                    int* __restrict__ bcur, int* __restrict__ off) {
    __shared__ int sd[256];
    int t = threadIdx.x;
    int v = (t < NB) ? bcnt[t] : 0;
    sd[t] = v; __syncthreads();
    for (int s = 1; s < 256; s <<= 1) {
        int x = (t >= s) ? sd[t - s] : 0;
        __syncthreads(); sd[t] += x; __syncthreads();
    }
    if (t < NB) { boff[t] = sd[t] - v; bcur[t] = 0; }
    if (t == 0) { boff[NB] = NEDGE; off[NNODE] = NEDGE; }
}

__global__ __launch_bounds__(256) void scatterA_kernel(const int* __restrict__ erow, const int* __restrict__ ecol,
                                                       const int* __restrict__ boff, int* __restrict__ bcur,
                                                       unsigned* __restrict__ bdata) {
    __shared__ int lh[224], gb[224];
    int t = threadIdx.x;
    if (t < 224) lh[t] = 0;
    __syncthreads();
    int base = blockIdx.x * 1024;
    int bb[4], rk[4]; unsigned pk[4];
    #pragma unroll
    for (int i = 0; i < 4; ++i) {
        int e = base + i * 256 + t;
        if (e < NEDGE) {
            int r = erow[e];
            bb[i] = r >> 8;
            pk[i] = ((unsigned)(r & 255) << 16) | (unsigned)ecol[e];
            rk[i] = atomicAdd(&lh[bb[i]], 1);
        } else bb[i] = -1;
    }
    __syncthreads();
    if (t < NB && lh[t] > 0) gb[t] = atomicAdd(&bcur[t], lh[t]);
    __syncthreads();
    #pragma unroll
    for (int i = 0; i < 4; ++i) {
        if (bb[i] >= 0) bdata[boff[bb[i]] + gb[bb[i]] + rk[i]] = pk[i];
    }
}

__global__ __launch_bounds__(256) void bucketB_kernel(const unsigned* __restrict__ bdata, const int* __restrict__ boff,
                                                      int* __restrict__ off, unsigned short* __restrict__ ccol) {
    __shared__ int lh[256], loff[256], lcur[256];
    int b = blockIdx.x, t = threadIdx.x;
    lh[t] = 0; lcur[t] = 0;
    __syncthreads();
    int lo = boff[b], hi = boff[b + 1];
    for (int e = lo + t; e < hi; e += 256) atomicAdd(&lh[bdata[e] >> 16], 1);
    __syncthreads();
    loff[t] = lh[t]; __syncthreads();
    for (int s = 1; s < 256; s <<= 1) {
        int x = (t >= s) ? loff[t - s] : 0;
        __syncthreads(); loff[t] += x; __syncthreads();
    }
    int row = b * 256 + t;
    if (row < NNODE) off[row] = lo + loff[t] - lh[t];
    __syncthreads();
    for (int e = lo + t; e < hi; e += 256) {
        unsigned v = bdata[e];
        int rlo = v >> 16;
        int p = atomicAdd(&lcur[rlo], 1);
        ccol[lo + loff[rlo] - lh[rlo] + p] = (unsigned short)(v & 0xffffu);
    }
}

// ---------------- GEMM: LDS-staged B, LDS-transposed coalesced epilogue, LDS column-stats ----------------
template<int KSTEPS, int KREAL, bool ABF16, bool FUSE, bool STATS>
__global__ __launch_bounds__(256, 4) void gemm_kernel(
    const void* __restrict__ Ap, const short* __restrict__ Wt,
    const float* __restrict__ psIn, const float* __restrict__ pqIn,
    const float* __restrict__ gammaIn, const float* __restrict__ betaIn,
    short* __restrict__ C, float* __restrict__ psOut, float* __restrict__ pqOut)
{
    constexpr int KP  = KSTEPS * 32;
    constexpr int LDK = KP + 8;                 // 272B+ row stride -> banks spread
    constexpr int CH  = KP / 8;                 // 16B chunks per row
    __shared__ short lw[DH * LDK];              // weight tile; reused as C-tile in epilogue
    __shared__ float lal[DH], lbe[DH];
    int tid = threadIdx.x;
    if constexpr (FUSE) {
        if (tid < DH) {
            float s = 0.f, q = 0.f;
            #pragma unroll 8
            for (int i = 0; i < NSLOT; ++i) { s += psIn[i * DH + tid]; q += pqIn[i * DH + tid]; }
            float mean = s * (1.f / NNODE);
            float var  = fmaxf(q * (1.f / NNODE) - mean * mean, 0.f);
            float a    = gammaIn[tid] * rsqrtf(var + 1e-5f);
            lal[tid] = a; lbe[tid] = betaIn[tid] - a * mean;
        }
    }
    // stage Wt (bf16, pre-converted) into LDS
    #pragma unroll 2
    for (int idx = tid; idx < DH * CH; idx += 256) {
        int r = idx / CH, c = idx % CH;
        *(bf16x8*)&lw[r * LDK + c * 8] = *(const bf16x8*)&Wt[r * KP + c * 8];
    }
    __syncthreads();

    int wave = tid >> 6, lane = tid & 63;
    int lr = lane & 15, lk = lane >> 4;
    int row  = blockIdx.x * 64 + wave * 16 + lr;
    int ksub = lk * 8;
    bool rok = row < NNODE;

    f32x4 acc[8];
    #pragma unroll
    for (int n = 0; n < 8; ++n) acc[n] = (f32x4){0.f, 0.f, 0.f, 0.f};

    if constexpr (ABF16) {
        bf16x8 araw[KSTEPS];
        #pragma unroll
        for (int kk = 0; kk < KSTEPS; ++kk) {
            if (rok) araw[kk] = *(const bf16x8*)((const short*)Ap + (size_t)row * KREAL + kk * 32 + ksub);
            else     araw[kk] = (bf16x8){0,0,0,0,0,0,0,0};
        }
        #pragma unroll
        for (int kk = 0; kk < KSTEPS; ++kk) {
            int k0 = kk * 32 + ksub;
            union { bf16x8 v; unsigned u[4]; } raw; raw.v = araw[kk];
            float va[8];
            #pragma unroll
            for (int e = 0; e < 4; ++e) { va[2*e] = bflo(raw.u[e]); va[2*e+1] = bfhi(raw.u[e]); }
            if constexpr (FUSE) {
                #pragma unroll
                for (int e = 0; e < 8; ++e)
                    va[e] = fmaxf(lal[k0 + e] * va[e] + lbe[k0 + e], 0.f);
            }
            union { bf16x8 v; unsigned u[4]; } a;
            #pragma unroll
            for (int e = 0; e < 4; ++e) a.u[e] = pkbf(va[2*e], va[2*e+1]);
            #pragma unroll
            for (int n = 0; n < 8; ++n) {
                bf16x8 bfrag = *(const bf16x8*)&lw[(n * 16 + lr) * LDK + kk * 32 + ksub];
                acc[n] = __builtin_amdgcn_mfma_f32_16x16x32_bf16(a.v, bfrag, acc[n], 0, 0, 0);
            }
        }
    } else {
        const float* arow = (const float*)Ap + (size_t)row * KREAL;
        float4 c0, c1, n0, n1;
        bool v0 = rok && (ksub + 8 <= KREAL);
        if (v0) { const float4* p = (const float4*)(arow + ksub); c0 = p[0]; c1 = p[1]; }
        else    { c0 = float4{0,0,0,0}; c1 = float4{0,0,0,0}; }
        #pragma unroll
        for (int kk = 0; kk < KSTEPS; ++kk) {
            if (kk + 1 < KSTEPS) {
                int k1 = (kk + 1) * 32 + ksub;
                bool vn = rok && (k1 + 8 <= KREAL);
                if (vn) { const float4* p = (const float4*)(arow + k1); n0 = p[0]; n1 = p[1]; }
                else    { n0 = float4{0,0,0,0}; n1 = float4{0,0,0,0}; }
            }
            float va[8];
            va[0]=c0.x; va[1]=c0.y; va[2]=c0.z; va[3]=c0.w;
            va[4]=c1.x; va[5]=c1.y; va[6]=c1.z; va[7]=c1.w;
            union { bf16x8 v; unsigned u[4]; } a;
            #pragma unroll
            for (int e = 0; e < 4; ++e) a.u[e] = pkbf(va[2*e], va[2*e+1]);
            #pragma unroll
            for (int n = 0; n < 8; ++n) {
                bf16x8 bfrag = *(const bf16x8*)&lw[(n * 16 + lr) * LDK + kk * 32 + ksub];
                acc[n] = __builtin_amdgcn_mfma_f32_16x16x32_bf16(a.v, bfrag, acc[n], 0, 0, 0);
            }
            c0 = n0; c1 = n1;
        }
    }

    // ---- epilogue: stage C-tile (64 rows x 128 bf16, stride 136) into lw, then coalesced stores ----
    constexpr int LDC = DH + 8;   // 136 shorts
    __syncthreads();              // all lw (weight) reads done
    #pragma unroll
    for (int n = 0; n < 8; ++n) {
        #pragma unroll
        for (int j = 0; j < 4; ++j) {
            int r = wave * 16 + lk * 4 + j;
            lw[r * LDC + n * 16 + lr] = f2bf(acc[n][j]);
        }
    }
    __syncthreads();

    int base = blockIdx.x * 64;
    #pragma unroll
    for (int i = 0; i < 4; ++i) {
        int c = tid + 256 * i;                 // 0..1023 chunks of 16B
        int r = c >> 4, ch = c & 15;
        int gr = base + r;
        if (gr < NNODE)
            *(bf16x8*)&C[(size_t)gr * DH + ch * 8] = *(bf16x8*)&lw[r * LDC + ch * 8];
    }

    if constexpr (STATS) {
        // column stats over the staged tile: threads 0-127 sum, 128-255 sum of squares
        int col = tid & 127;
        bool doq = tid >= 128;
        float accv = 0.f;
        int rmax = min(64, NNODE - base);
        for (int r = 0; r < rmax; ++r) {
            float v = bfs(((const unsigned short*)lw)[r * LDC + col]);
            accv += doq ? v * v : v;
        }
        int slot = (blockIdx.x & (NSLOT - 1)) * DH + col;
        if (doq) atomicAdd(&pqOut[slot], accv);
        else     atomicAdd(&psOut[slot], accv);
    }
}

// ---------------- aggregation: z = Adj@y + (1+eps)*y, bf16 in/out, NO stats, NT z-store ----------------
__global__ __launch_bounds__(256) void agg_kernel(
    const short* __restrict__ yb, short* __restrict__ zb,
    const int* __restrict__ off, const unsigned short* __restrict__ ccol,
    const float* __restrict__ epsv, int layer)
{
    int tid = threadIdx.x;
    int wave = tid >> 6, t = tid & 63;
    int node = blockIdx.x * 4 + wave;
    if (node >= NNODE) return;
    const unsigned* y2 = (const unsigned*)yb;
    int k = off[node], k1 = off[node + 1];
    float s0=0,s1=0,t0=0,t1=0,u0=0,u1=0,v0=0,v1=0;
    for (; k + 7 < k1; k += 8) {
        int c0 = ccol[k],   c1 = ccol[k+1], c2 = ccol[k+2], c3 = ccol[k+3];
        int c4 = ccol[k+4], c5 = ccol[k+5], c6 = ccol[k+6], c7 = ccol[k+7];
        unsigned a = y2[(size_t)c0 * 64 + t];
        unsigned b = y2[(size_t)c1 * 64 + t];
        unsigned c = y2[(size_t)c2 * 64 + t];
        unsigned d = y2[(size_t)c3 * 64 + t];
        unsigned e = y2[(size_t)c4 * 64 + t];
        unsigned f = y2[(size_t)c5 * 64 + t];
        unsigned g = y2[(size_t)c6 * 64 + t];
        unsigned h = y2[(size_t)c7 * 64 + t];
        s0 += bflo(a) + bflo(e); s1 += bfhi(a) + bfhi(e);
        t0 += bflo(b) + bflo(f); t1 += bfhi(b) + bfhi(f);
        u0 += bflo(c) + bflo(g); u1 += bfhi(c) + bfhi(g);
        v0 += bflo(d) + bflo(h); v1 += bfhi(d) + bfhi(h);
    }
    for (; k + 3 < k1; k += 4) {
        int c0 = ccol[k], c1 = ccol[k+1], c2 = ccol[k+2], c3 = ccol[k+3];
        unsigned a = y2[(size_t)c0 * 64 + t];
        unsigned b = y2[(size_t)c1 * 64 + t];
        unsigned c = y2[(size_t)c2 * 64 + t];
        unsigned d = y2[(size_t)c3 * 64 + t];
        s0 += bflo(a); s1 += bfhi(a); t0 += bflo(b); t1 += bfhi(b);
        u0 += bflo(c); u1 += bfhi(c); v0 += bflo(d); v1 += bfhi(d);
    }
    for (; k < k1; ++k) {
        unsigned a = y2[(size_t)ccol[k] * 64 + t];
        s0 += bflo(a); s1 += bfhi(a);
    }
    unsigned sv = y2[(size_t)node * 64 + t];
    float e = 1.f + epsv[layer];
    float rx = (s0 + t0) + (u0 + v0) + e * bflo(sv);
    float ry = (s1 + t1) + (u1 + v1) + e * bfhi(sv);
    __builtin_nontemporal_store(pkbf(rx, ry), (unsigned*)zb + (size_t)node * 64 + t);
}

// ---------------- Z BN stats (separate pass, vectorized) ----------------
__global__ __launch_bounds__(256) void statsZ_kernel(const short* __restrict__ zb,
                                                     float* __restrict__ ps, float* __restrict__ pq) {
    __shared__ float red[4][DH];
    int t = threadIdx.x;
    int cg = t & 63, rg = t >> 6;
    const unsigned* z2 = (const unsigned*)zb;
    int r0 = blockIdx.x * 196, r1 = min(r0 + 196, NNODE);
    float s0 = 0.f, s1 = 0.f, q0 = 0.f, q1 = 0.f;
    for (int r = r0 + rg; r < r1; r += 4) {
        unsigned v = z2[(size_t)r * 64 + cg];
        float a = bflo(v), b = bfhi(v);
        s0 += a; q0 += a * a; s1 += b; q1 += b * b;
    }
    red[rg][2 * cg] = s0; red[rg][2 * cg + 1] = s1;
    __syncthreads();
    if (t < DH) {
        float s = red[0][t] + red[1][t] + red[2][t] + red[3][t];
        atomicAdd(&ps[(blockIdx.x & (NSLOT - 1)) * DH + t], s);
    }
    __syncthreads();
    red[rg][2 * cg] = q0; red[rg][2 * cg + 1] = q1;
    __syncthreads();
    if (t < DH) {
        float q = red[0][t] + red[1][t] + red[2][t] + red[3][t];
        atomicAdd(&pq[(blockIdx.x & (NSLOT - 1)) * DH + t], q);
    }
}

// ---------------- pooling ----------------
__global__ __launch_bounds__(256) void poolx_kernel(const float* __restrict__ x,
                                                    const int* __restrict__ gs, float* __restrict__ out) {
    int g = blockIdx.x >> 4, sp = blockIdx.x & 15, t = threadIdx.x;
    if (t >= DIN) return;
    int lo = gs[g], hi = gs[g + 1], len = hi - lo;
    int r0 = lo + (len * sp >> 4), r1 = lo + (len * (sp + 1) >> 4);
    float a0 = 0.f, a1 = 0.f;
    int r = r0;
    for (; r + 1 < r1; r += 2) {
        a0 += x[(size_t)r * DIN + t];
        a1 += x[(size_t)(r + 1) * DIN + t];
    }
    if (r < r1) a0 += x[(size_t)r * DIN + t];
    atomicAdd(&out[g * OUTW + t], a0 + a1);
}

__global__ __launch_bounds__(128) void pool_kernel(const short* __restrict__ rep,
                                                   const float* __restrict__ psIn, const float* __restrict__ pqIn,
                                                   const float* __restrict__ gammaIn, const float* __restrict__ betaIn,
                                                   const int* __restrict__ gs, float* __restrict__ out, int ooff) {
    int c = threadIdx.x;
    float s = 0.f, q = 0.f;
    #pragma unroll 8
    for (int i = 0; i < NSLOT; ++i) { s += psIn[i * DH + c]; q += pqIn[i * DH + c]; }
    float mean = s * (1.f / NNODE);
    float var  = fmaxf(q * (1.f / NNODE) - mean * mean, 0.f);
    float a    = gammaIn[c] * rsqrtf(var + 1e-5f);
    float b    = betaIn[c] - a * mean;

    int g = blockIdx.x >> 3, sp = blockIdx.x & 7;
    int lo = gs[g], hi = gs[g + 1], len = hi - lo;
    int r0 = lo + (len * sp >> 3), r1 = lo + (len * (sp + 1) >> 3);
    float acc = 0.f;
    const unsigned short* rp = (const unsigned short*)rep;
    for (int r = r0; r < r1; ++r) acc += fmaxf(a * bfs(rp[(size_t)r * DH + c]) + b, 0.f);
    atomicAdd(&out[g * OUTW + ooff + c], acc);
}

// ---------------- launch ----------------
extern "C" void kernel_launch(void* const* d_in, const int* in_sizes, int n_in,
                              void* d_out, int out_size, void* d_ws, size_t ws_size,
                              hipStream_t stream)
{
    const float* x    = (const float*)d_in[0];
    const int*   erow = (const int*)d_in[1];
    const int*   ecol = (const int*)d_in[2];
    const int*   gid  = (const int*)d_in[3];
    const float* eps  = (const float*)d_in[4];
    const float* w1_0 = (const float*)d_in[5];
    const float* g1_0 = (const float*)d_in[7];
    const float* be10 = (const float*)d_in[8];
    const float* w2_0 = (const float*)d_in[9];
    const float* gbn0 = (const float*)d_in[11];
    const float* bbn0 = (const float*)d_in[12];
    const float* w1_r = (const float*)d_in[13];
    const float* g1_r = (const float*)d_in[15];
    const float* be1r = (const float*)d_in[16];
    const float* w2_r = (const float*)d_in[17];
    const float* gbnr = (const float*)d_in[19];
    const float* bbnr = (const float*)d_in[20];
    float* out = (float*)d_out;

    // workspace layout
    short* Zb = (short*)d_ws;                       // NNODE*DH bf16
    short* Y  = Zb + (size_t)NNODE * DH;
    short* RA = Y  + (size_t)NNODE * DH;
    short* RB = RA + (size_t)NNODE * DH;
    short* Wt = RB + (size_t)NNODE * DH;            // 143360 shorts
    float* stats = (float*)(Wt + 143360);           // 4 layers * 4 * NSLOT*DH = 65536 floats
    int* bcnt = (int*)(stats + 65536);              // 256
    int* boff = bcnt + 256;
    int* bcur = boff + 256;
    int* off  = bcur + 256;                         // 50016
    unsigned* bdata = (unsigned*)(off + 50016);     // NEDGE
    unsigned short* ccol = (unsigned short*)(bdata + NEDGE);  // NEDGE u16
    int* gs = (int*)(ccol + NEDGE);                 // 129

    prezero_kernel<<<1, 256, 0, stream>>>(bcnt);
    setup_kernel<<<2292, 256, 0, stream>>>(out, stats, bcnt, gid, gs,
                                           w1_0, w2_0, w1_r, w2_r, Wt, erow);
    scanB_kernel<<<1, 256, 0, stream>>>(bcnt, boff, bcur, off);
    scatterA_kernel<<<782, 256, 0, stream>>>(erow, ecol, boff, bcur, bdata);
    bucketB_kernel<<<NB, 256, 0, stream>>>(bdata, boff, off, ccol);
    poolx_kernel<<<NGRAPH * 16, 256, 0, stream>>>(x, gs, out);

    const int GB = (NNODE + 63) / 64;   // 782
    const int LS = NSLOT * DH;
    for (int l = 0; l < 4; ++l) {
        const short* Wt1 = (l == 0) ? Wt : Wt + 28672 + (size_t)(2 * l - 1) * 16384;
        const short* Wt2 = (l == 0) ? Wt + 28672 : Wt + 28672 + (size_t)(2 * l) * 16384;
        const float* G1 = (l == 0) ? g1_0 : (g1_r + (l - 1) * DH);
        const float* B1 = (l == 0) ? be10 : (be1r + (l - 1) * DH);
        const float* G2 = (l == 0) ? gbn0 : (gbnr + (l - 1) * DH);
        const float* B2 = (l == 0) ? bbn0 : (bbnr + (l - 1) * DH);
        short* rep = (l & 1) ? RB : RA;
        float* psZ = stats + l * 4 * LS;
        float* pqZ = psZ + LS;
        float* psA = pqZ + LS;
        float* pqA = psA + LS;

        if (l == 0)
            gemm_kernel<7, 200, false, false, false><<<GB, 256, 0, stream>>>(
                x, Wt1, nullptr, nullptr, nullptr, nullptr, Y, nullptr, nullptr);
        else {
            const short* prev = ((l - 1) & 1) ? RB : RA;
            float* psAp = stats + (l - 1) * 4 * LS + 2 * LS;
            float* pqAp = psAp + LS;
            const float* G2prev = (l - 1 == 0) ? gbn0 : (gbnr + (l - 2) * DH);
            const float* B2prev = (l - 1 == 0) ? bbn0 : (bbnr + (l - 2) * DH);
            gemm_kernel<4, 128, true, true, false><<<GB, 256, 0, stream>>>(
                prev, Wt1, psAp, pqAp, G2prev, B2prev, Y, nullptr, nullptr);
        }
        agg_kernel<<<(NNODE + 3) / 4, 256, 0, stream>>>(Y, Zb, off, ccol, eps, l);
        statsZ_kernel<<<256, 256, 0, stream>>>(Zb, psZ, pqZ);
        gemm_kernel<4, 128, true, true, true><<<GB, 256, 0, stream>>>(
            Zb, Wt2, psZ, pqZ, G1, B1, rep, psA, pqA);
        pool_kernel<<<NGRAPH * 8, 128, 0, stream>>>(rep, psA, pqA, G2, B2, gs, out, DIN + l * DH);
    }
}